// Round 16
// baseline (206.324 us; speedup 1.0000x reference)
//
#include <hip/hip_runtime.h>
#include <hip/hip_bf16.h>
#include <math.h>

// ---------------- problem constants ----------------
#define B_    128
#define N_    196
#define E_    768
#define K_    8
#define D_    128
#define BNR   (B_*N_)        // 25088 rows
#define ITERS 5

// ws layout (float units)
#define OFF_PART   0          // 512 partials + counter at [512]
#define OFF_SDEC   1024       // ushort[1024*128] = 65536 floats
#define OFF_WBF    66560      // ushort region (incl. WMt)
#define OFF_KPBF   640000     // ushort[128*208*128]
#define OFF_VPTBF  2343936    // ushort[128*128*224]
#define OFF_ABF    4178944    // ushort[25088*768] (aliased by sf/h1/h2 after proj)

typedef __attribute__((ext_vector_type(8))) short bf16x8;
typedef __attribute__((ext_vector_type(4))) float f32x4;

#define MFMA16(a, b, c) __builtin_amdgcn_mfma_f32_16x16x32_bf16(a, b, c, 0, 0, 0)

__device__ __forceinline__ float wave_red_sum64(float v) {
    #pragma unroll
    for (int o = 32; o > 0; o >>= 1) v += __shfl_xor(v, o);
    return v;
}

__device__ __forceinline__ unsigned short f2bf(float v) {
    union { float f; unsigned int u; } c; c.f = v;
    unsigned int u = c.u + 0x7fffu + ((c.u >> 16) & 1u);  // RNE
    return (unsigned short)(u >> 16);
}

__device__ __forceinline__ void gl_lds16(const void* g, void* l) {
    __builtin_amdgcn_global_load_lds(
        (const __attribute__((address_space(1))) unsigned int*)g,
        (__attribute__((address_space(3))) unsigned int*)l, 16, 0, 0);
}

// chunk-XOR swizzled LDS addressing (8-bf16 = 16B chunks)
__device__ __forceinline__ int swz128(int row, int j) {
    return row * 128 + ((((j >> 3) ^ (row & 7))) << 3) + (j & 7);
}
__device__ __forceinline__ int swz256(int row, int j) {
    return row * 256 + ((((j >> 3) ^ (row & 7))) << 3) + (j & 7);
}
__device__ __forceinline__ bf16x8 ldA128(const unsigned short* base, int row, int kq, int ks) {
    int ch = (ks * 4 + kq) ^ (row & 7);
    return *(const bf16x8*)(base + row * 128 + ch * 8);
}
__device__ __forceinline__ bf16x8 ldA256(const unsigned short* base, int row, int kq, int ks) {
    int ch = (ks * 4 + kq) ^ (row & 7);
    return *(const bf16x8*)(base + row * 256 + ch * 8);
}
__device__ __forceinline__ bf16x8 ldW128(const unsigned short* W, int row, int ks, int kq) {
    return *(const bf16x8*)(W + (size_t)row * 128 + ks * 32 + kq * 8);
}

// ---------------- K0: merged prep: wfold (blocks 0-5) + conversions (6-517) + padzero (518-1157) ----------------
struct WCEnt { const float* s; unsigned short* d; int t0; };
struct WCArgs { WCEnt m[8]; };

__global__ __launch_bounds__(256) void prep_all_k(const float* __restrict__ Wq,
                                                  const float* __restrict__ Wk,
                                                  unsigned short* __restrict__ WMt,
                                                  WCArgs a,
                                                  unsigned short* __restrict__ kpb,
                                                  unsigned short* __restrict__ vpt,
                                                  unsigned int* __restrict__ counter) {
    __shared__ __align__(16) unsigned short Aq[128 * 128];
    __shared__ __align__(16) unsigned short Bk[128 * 128];
    int bid = blockIdx.x;
    int t = threadIdx.x;
    if (bid == 6 && t == 0) *counter = 0;   // reset recon-loss block counter each call
    if (bid < 6) {
        const float s = 0.08838834764831845f;  // 128^-0.5
        int e0 = bid * 128;
        for (int idx = t; idx < 16384; idx += 256) {
            int o = idx >> 7, c = idx & 127;
            Aq[swz128(c, o)] = f2bf(Wq[(size_t)o * 128 + c]);           // Aq[i][o] = Wq[o][i]
            Bk[swz128(c, o)] = f2bf(Wk[(size_t)o * 768 + e0 + c] * s);  // Bk[e][o] = s*Wk[o][e]
        }
        __syncthreads();
        int w = t >> 6, l = t & 63;
        int wr = w >> 1, wc = w & 1, fr = l & 15, kq = l >> 4;
        f32x4 acc[4][4];
        #pragma unroll
        for (int mi = 0; mi < 4; ++mi)
            #pragma unroll
            for (int nj = 0; nj < 4; ++nj) acc[mi][nj] = (f32x4){0.f, 0.f, 0.f, 0.f};
        #pragma unroll
        for (int ks = 0; ks < 4; ++ks) {
            bf16x8 af[4], bfr[4];
            #pragma unroll
            for (int mi = 0; mi < 4; ++mi) af[mi] = ldA128(Aq, wr * 64 + mi * 16 + fr, kq, ks);
            #pragma unroll
            for (int nj = 0; nj < 4; ++nj) bfr[nj] = ldA128(Bk, wc * 64 + nj * 16 + fr, kq, ks);
            #pragma unroll
            for (int mi = 0; mi < 4; ++mi)
                #pragma unroll
                for (int nj = 0; nj < 4; ++nj)
                    acc[mi][nj] = MFMA16(af[mi], bfr[nj], acc[mi][nj]);
        }
        #pragma unroll
        for (int mi = 0; mi < 4; ++mi) {
            int rowbase = wr * 64 + mi * 16 + kq * 4;
            #pragma unroll
            for (int nj = 0; nj < 4; ++nj) {
                int col = e0 + wc * 64 + nj * 16 + fr;
                #pragma unroll
                for (int r = 0; r < 4; ++r)
                    WMt[(size_t)(rowbase + r) * 768 + col] = f2bf(acc[mi][nj][r]);
            }
        }
    } else if (bid < 518) {
        int cbid = bid - 6, i = 0;
        #pragma unroll
        for (int j = 1; j < 8; ++j) if (cbid >= a.m[j].t0) i = j;
        int off = (cbid - a.m[i].t0) * 2048 + t * 8;
        const float* s = a.m[i].s + off;
        unsigned short* d = a.m[i].d + off;
        float4 v0 = *(const float4*)s, v1 = *(const float4*)(s + 4);
        ushort4 o0, o1;
        o0.x = f2bf(v0.x); o0.y = f2bf(v0.y); o0.z = f2bf(v0.z); o0.w = f2bf(v0.w);
        o1.x = f2bf(v1.x); o1.y = f2bf(v1.y); o1.z = f2bf(v1.z); o1.w = f2bf(v1.w);
        *(ushort4*)d = o0; *(ushort4*)(d + 4) = o1;
    } else {
        int i = (bid - 518) * 256 + t;   // ushort4 index, 163840 total
        ushort4 z = {0, 0, 0, 0};
        if (i < 49152) {                 // kp pads: 128 b x 12 rows x 128
            int q = i * 4;
            int b = q / 1536, off = q - b * 1536;
            *(ushort4*)(kpb + ((size_t)b * 208 + 196) * 128 + off) = z;
        } else {                          // vpT pads: per (b,d) cols 196..223
            int c = i - 49152;            // 0..114687
            int bd = c / 7, cc = c - bd * 7;
            *(ushort4*)(vpt + (size_t)bd * 224 + 196 + cc * 4) = z;
        }
    }
}

// ---------------- K1: one-pass LayerNorm(features) -> bf16 ----------------
__global__ __launch_bounds__(256) void ln_bf16_k(const float* __restrict__ f,
                                                 const float* __restrict__ g,
                                                 const float* __restrict__ bv,
                                                 unsigned short* __restrict__ out) {
    int wid = blockIdx.x * 4 + (threadIdx.x >> 6);   // one wave per row
    int lane = threadIdx.x & 63;
    const float* row = f + (size_t)wid * E_;
    float4 x[3];
    float s = 0.f, s2 = 0.f;
    #pragma unroll
    for (int c = 0; c < 3; ++c) {
        x[c] = *(const float4*)(row + c * 256 + lane * 4);
        s  += x[c].x + x[c].y + x[c].z + x[c].w;
        s2 += x[c].x * x[c].x + x[c].y * x[c].y + x[c].z * x[c].z + x[c].w * x[c].w;
    }
    s  = wave_red_sum64(s);
    s2 = wave_red_sum64(s2);
    float m = s * (1.f / E_);
    float rs = rsqrtf(s2 * (1.f / E_) - m * m + 1e-5f);
    #pragma unroll
    for (int c = 0; c < 3; ++c) {
        float4 g4 = *(const float4*)(g + c * 256 + lane * 4);
        float4 b4 = *(const float4*)(bv + c * 256 + lane * 4);
        ushort4 o;
        o.x = f2bf((x[c].x - m) * rs * g4.x + b4.x);
        o.y = f2bf((x[c].y - m) * rs * g4.y + b4.y);
        o.z = f2bf((x[c].z - m) * rs * g4.z + b4.z);
        o.w = f2bf((x[c].w - m) * rs * g4.w + b4.w);
        *(ushort4*)(out + (size_t)wid * E_ + c * 256 + lane * 4) = o;
    }
}

// ---------------- K2: dual-output bf16 MFMA GEMM: kpq (row-major) + vpT (LDS-transposed) ----------------
__global__ __launch_bounds__(512) void mfma_proj_k(const unsigned short* __restrict__ Abf,
                                                   const unsigned short* __restrict__ WMt,
                                                   const unsigned short* __restrict__ Wv_bf,
                                                   unsigned short* __restrict__ kpq_bf,
                                                   unsigned short* __restrict__ vpT_bf) {
    __shared__ __align__(16) unsigned short As[128 * 64];   // 1024 chunks
    __shared__ __align__(16) unsigned short Bs[256 * 64];   // 2048 chunks; reused as transpose buf
    const int t = threadIdx.x, w = t >> 6, l = t & 63;
    const int m0 = blockIdx.x * 128;
    const int wr = w >> 2, wc = w & 3;
    const int fr = l & 15, kq = l >> 4;
    f32x4 acc[4][4];
    #pragma unroll
    for (int mi = 0; mi < 4; ++mi)
        #pragma unroll
        for (int nj = 0; nj < 4; ++nj) acc[mi][nj] = (f32x4){0.f, 0.f, 0.f, 0.f};

    for (int ks = 0; ks < E_; ks += 64) {
        __syncthreads();
        #pragma unroll
        for (int j = 0; j < 2; ++j) {      // A: 1024 chunks
            int ci = j * 512 + (w << 6) + l;
            int r = ci >> 3, c = ci & 7, cg = c ^ (r & 7);
            gl_lds16(Abf + (size_t)(m0 + r) * E_ + ks + cg * 8,
                     As + (size_t)(j * 512 + (w << 6)) * 8);
        }
        #pragma unroll
        for (int j = 0; j < 4; ++j) {      // B: 2048 chunks (256 rows)
            int ci = j * 512 + (w << 6) + l;
            int r = ci >> 3, c = ci & 7, cg = c ^ (r & 7);
            const unsigned short* src = (r < 128)
                ? WMt   + (size_t)r * E_ + ks + cg * 8
                : Wv_bf + (size_t)(r - 128) * E_ + ks + cg * 8;
            gl_lds16(src, Bs + (size_t)(j * 512 + (w << 6)) * 8);
        }
        __syncthreads();
        #pragma unroll
        for (int kk = 0; kk < 2; ++kk) {
            bf16x8 af[4], bfr[4];
            #pragma unroll
            for (int mi = 0; mi < 4; ++mi) {
                int rr = wr * 64 + mi * 16 + fr;
                af[mi] = *(const bf16x8*)(As + rr * 64 + (((kk * 4 + kq) ^ (rr & 7))) * 8);
            }
            #pragma unroll
            for (int nj = 0; nj < 4; ++nj) {
                int rr = wc * 64 + nj * 16 + fr;
                bfr[nj] = *(const bf16x8*)(Bs + rr * 64 + (((kk * 4 + kq) ^ (rr & 7))) * 8);
            }
            #pragma unroll
            for (int mi = 0; mi < 4; ++mi)
                #pragma unroll
                for (int nj = 0; nj < 4; ++nj)
                    acc[mi][nj] = MFMA16(af[mi], bfr[nj], acc[mi][nj]);
        }
    }
    __syncthreads();   // all LDS MFMA reads complete before Bs reuse
    if (wc < 2) {
        // kpq quadrants: row-major padded per-batch writes
        #pragma unroll
        for (int mi = 0; mi < 4; ++mi) {
            int rowbase = m0 + wr * 64 + mi * 16 + kq * 4;
            #pragma unroll
            for (int r = 0; r < 4; ++r) {
                int m = rowbase + r;
                int b = m / 196, rr = m - b * 196;
                size_t o = ((size_t)b * 208 + rr) * 128;
                #pragma unroll
                for (int nj = 0; nj < 4; ++nj)
                    kpq_bf[o + wc * 64 + nj * 16 + fr] = f2bf(acc[mi][nj][r]);
            }
        }
    } else {
        // vp quadrants: transpose into Bs[d][tok] with XOR chunk swizzle
        int dbase = (wc - 2) * 64;
        #pragma unroll
        for (int mi = 0; mi < 4; ++mi) {
            int tok = wr * 64 + mi * 16 + kq * 4;
            #pragma unroll
            for (int nj = 0; nj < 4; ++nj) {
                int d = dbase + nj * 16 + fr;
                ushort4 pk;
                pk.x = f2bf(acc[mi][nj][0]); pk.y = f2bf(acc[mi][nj][1]);
                pk.z = f2bf(acc[mi][nj][2]); pk.w = f2bf(acc[mi][nj][3]);
                *(ushort4*)(Bs + d * 128 + (tok ^ ((d & 7) << 3))) = pk;
            }
        }
    }
    __syncthreads();
    // coalesced vpT store: thread t -> d = t>>2, m-range (t&3)*32..+32
    {
        int d = t >> 2, mg = t & 3;
        #pragma unroll
        for (int sc = 0; sc < 4; ++sc) {
            int mstart = mg * 32 + sc * 8;
            int cm = mstart >> 3;
            const unsigned short* src = Bs + d * 128 + ((cm ^ (d & 7)) << 3);
            int g0 = m0 + mstart;
            int b0 = g0 / 196, rr0 = g0 - b0 * 196;
            int b7 = (g0 + 7) / 196;
            if (b0 == b7) {
                unsigned short* dst = vpT_bf + ((size_t)b0 * 128 + d) * 224 + rr0;
                *(ushort4*)(dst)     = *(const ushort4*)(src);
                *(ushort4*)(dst + 4) = *(const ushort4*)(src + 4);
            } else {
                #pragma unroll
                for (int e = 0; e < 8; ++e) {
                    int g = g0 + e;
                    int bb = g / 196, rr = g - bb * 196;
                    vpT_bf[((size_t)bb * 128 + d) * 224 + rr] = src[e];
                }
            }
        }
    }
}

// ---------------- K2b: generic MLP-layer MFMA GEMM (R6-proven staging) ----------------
template<int KTOT, int EPI>
__global__ __launch_bounds__(256) void mfma_mlp_k(const unsigned short* __restrict__ A,
                                                  const unsigned short* __restrict__ Bw,
                                                  const float* __restrict__ bias,
                                                  unsigned short* __restrict__ out_bf,
                                                  float* __restrict__ out_f,
                                                  int ldN) {
    __shared__ __align__(16) unsigned short As[128 * 64];
    __shared__ __align__(16) unsigned short Bs[128 * 64];
    const int t = threadIdx.x, w = t >> 6, l = t & 63;
    const int m0 = blockIdx.x * 128;
    const int n0 = blockIdx.y * 128;
    const int wr = w >> 1, wc = w & 1;
    const int fr = l & 15, kq = l >> 4;
    f32x4 acc[4][4];
    #pragma unroll
    for (int mi = 0; mi < 4; ++mi)
        #pragma unroll
        for (int nj = 0; nj < 4; ++nj) acc[mi][nj] = (f32x4){0.f, 0.f, 0.f, 0.f};

    for (int ks = 0; ks < KTOT; ks += 64) {
        __syncthreads();
        #pragma unroll
        for (int j = 0; j < 4; ++j) {
            int ci = (w << 8) + (j << 6) + l;
            int r = ci >> 3, c = ci & 7;
            int cg = c ^ (r & 7);
            gl_lds16(A  + (size_t)(m0 + r) * KTOT + ks + cg * 8,
                     As + (size_t)((w << 8) + (j << 6)) * 8);
            gl_lds16(Bw + (size_t)(n0 + r) * KTOT + ks + cg * 8,
                     Bs + (size_t)((w << 8) + (j << 6)) * 8);
        }
        __syncthreads();
        #pragma unroll
        for (int kk = 0; kk < 2; ++kk) {
            bf16x8 af[4], bfr[4];
            int ch = (kk * 4 + kq) ^ (fr & 7);
            #pragma unroll
            for (int mi = 0; mi < 4; ++mi)
                af[mi] = *(const bf16x8*)(As + (wr * 64 + mi * 16 + fr) * 64 + ch * 8);
            #pragma unroll
            for (int nj = 0; nj < 4; ++nj)
                bfr[nj] = *(const bf16x8*)(Bs + (wc * 64 + nj * 16 + fr) * 64 + ch * 8);
            #pragma unroll
            for (int mi = 0; mi < 4; ++mi)
                #pragma unroll
                for (int nj = 0; nj < 4; ++nj)
                    acc[mi][nj] = MFMA16(af[mi], bfr[nj], acc[mi][nj]);
        }
    }
    #pragma unroll
    for (int mi = 0; mi < 4; ++mi) {
        int rowbase = m0 + wr * 64 + mi * 16 + kq * 4;
        #pragma unroll
        for (int nj = 0; nj < 4; ++nj) {
            int col = n0 + wc * 64 + nj * 16 + fr;
            float bc = bias[col];
            #pragma unroll
            for (int r = 0; r < 4; ++r) {
                float v = acc[mi][nj][r] + bc;
                if (EPI == 0)
                    out_bf[(size_t)(rowbase + r) * ldN + col] = f2bf(fmaxf(v, 0.f));
                else
                    out_f[(size_t)(rowbase + r) * ldN + col] = v;
            }
        }
    }
}

// ---------------- K3: persistent per-batch slot-attention iterations (MFMA) ----------------
// R10/R15 8-phase structure (proven 64 us). No register hoists: hipcc caps
// 512-thread kernels at 128 VGPR and rematerializes/spills any hoist (R11/R12/R15).
__global__ __launch_bounds__(512) void slot_iter_mfma(
    const float* __restrict__ noise,
    const float* __restrict__ lsg, const float* __restrict__ lsb,
    const float* __restrict__ log_, const float* __restrict__ lob,
    const float* __restrict__ ldg_, const float* __restrict__ ldb_,
    const float* __restrict__ mup, const float* __restrict__ lsig,
    const unsigned short* __restrict__ Wih_bf,
    const unsigned short* __restrict__ Whh_bf,
    const float* __restrict__ bih, const float* __restrict__ bhh,
    const unsigned short* __restrict__ W1_bf, const float* __restrict__ mb1,
    const unsigned short* __restrict__ W2_bf, const float* __restrict__ mb2,
    const unsigned short* __restrict__ kpq_bf,
    const unsigned short* __restrict__ vpT_bf,
    float* __restrict__ out_slots, float* __restrict__ out_attn,
    unsigned short* __restrict__ sdec_bf) {

    __shared__ float slots[8][128];
    __shared__ float attn[208][9];
    __shared__ float colpart[8][8];
    __shared__ __align__(16) unsigned short sln_bf[2048];
    __shared__ __align__(16) unsigned short upd_bf[2048];
    __shared__ __align__(16) unsigned short slots_bf[2048];
    __shared__ __align__(16) unsigned short h_bf[2048];
    __shared__ __align__(16) unsigned short attnT_bf[4096];

    const int b = blockIdx.x, t = threadIdx.x;
    const int lane = t & 63, w = t >> 6;
    const int fr = lane & 15, kq = lane >> 4;

    for (int i = t; i < 2048; i += 512) {
        sln_bf[i] = 0; upd_bf[i] = 0; slots_bf[i] = 0; h_bf[i] = 0;
    }
    for (int i = t; i < 4096; i += 512) attnT_bf[i] = 0;

    for (int idx = t; idx < 1024; idx += 512) {
        int k = idx >> 7, d = idx & 127;
        float v = noise[(size_t)b * 1024 + idx] * expf(lsig[d]) + mup[d];
        slots[k][d] = v;
        slots_bf[swz128(k, d)] = f2bf(v);
    }
    __syncthreads();

    for (int it = 0; it < ITERS; ++it) {
        bool last = (it == ITERS - 1);
        // (a) LN_slot -> sln_bf (wave w owns slot w)
        {
            float x0 = slots[w][lane], x1 = slots[w][lane + 64];
            float s  = wave_red_sum64(x0 + x1);
            float s2 = wave_red_sum64(x0 * x0 + x1 * x1);
            float m = s * 0.0078125f;
            float rs = rsqrtf(s2 * 0.0078125f - m * m + 1e-5f);
            sln_bf[swz128(w, lane)]      = f2bf((x0 - m) * rs * lsg[lane]      + lsb[lane]);
            sln_bf[swz128(w, lane + 64)] = f2bf((x1 - m) * rs * lsg[lane + 64] + lsb[lane + 64]);
        }
        __syncthreads();
        // (c) logits = kpq @ sln^T, softmax over slots -> attn LDS + colpart
        {
            float cp = 0.f;
            #pragma unroll
            for (int p = 0; p < 2; ++p) {
                int tt = w + p * 8;
                if (tt <= 12) {
                    f32x4 acc = {0.f, 0.f, 0.f, 0.f};
                    const unsigned short* kpr = kpq_bf + ((size_t)b * 208 + tt * 16 + fr) * 128;
                    #pragma unroll
                    for (int ks = 0; ks < 4; ++ks)
                        acc = MFMA16(*(const bf16x8*)(kpr + ks * 32 + kq * 8),
                                     ldA128(sln_bf, fr, kq, ks), acc);
                    #pragma unroll
                    for (int r = 0; r < 4; ++r) {
                        float v = acc[r];
                        float mx = fmaxf(v, __shfl_xor(v, 1));
                        mx = fmaxf(mx, __shfl_xor(mx, 2));
                        mx = fmaxf(mx, __shfl_xor(mx, 4));
                        float e = expf(v - mx);
                        float sm = e;
                        sm += __shfl_xor(sm, 1); sm += __shfl_xor(sm, 2); sm += __shfl_xor(sm, 4);
                        float a = e / sm;
                        int tok = tt * 16 + kq * 4 + r;
                        bool valid = (tok < 196);
                        if (fr < 8 && valid) attn[tok][fr] = a;
                        cp += valid ? a : 0.f;
                    }
                }
            }
            cp += __shfl_xor(cp, 16);
            cp += __shfl_xor(cp, 32);
            if (lane < 8) colpart[w][lane] = cp;
        }
        __syncthreads();
        // (e) normalize over tokens -> attnT_bf (+ out_attn last iter)
        {
            int k = t & 7;
            float cs = colpart[0][k] + colpart[1][k] + colpart[2][k] + colpart[3][k]
                     + colpart[4][k] + colpart[5][k] + colpart[6][k] + colpart[7][k]
                     + 196.0f * 1e-8f;
            float inv = 1.f / cs;
            for (int idx = t; idx < 1568; idx += 512) {
                int n = idx >> 3;
                float raw = attn[n][k];
                attnT_bf[swz256(k, n)] = f2bf((raw + 1e-8f) * inv);
                if (last) out_attn[((size_t)b * 196 + n) * 8 + k] = raw;
            }
        }
        __syncthreads();
        // (f) updates = attn_norm^T @ v -> upd_bf
        {
            f32x4 acc = {0.f, 0.f, 0.f, 0.f};
            const unsigned short* vpr = vpT_bf + ((size_t)b * 128 + w * 16 + fr) * 224;
            #pragma unroll
            for (int ks = 0; ks < 7; ++ks)
                acc = MFMA16(ldA256(attnT_bf, fr, kq, ks),
                             *(const bf16x8*)(vpr + ks * 32 + kq * 8), acc);
            if (kq < 2) {
                #pragma unroll
                for (int r = 0; r < 4; ++r)
                    upd_bf[swz128(kq * 4 + r, w * 16 + fr)] = f2bf(acc[r]);
            }
        }
        __syncthreads();
        // (g) GRU
        {
            f32x4 gi0 = {0,0,0,0}, gi1 = {0,0,0,0}, gi2 = {0,0,0,0};
            f32x4 gh0 = {0,0,0,0}, gh1 = {0,0,0,0}, gh2 = {0,0,0,0};
            #pragma unroll
            for (int ks = 0; ks < 4; ++ks) {
                bf16x8 au = ldA128(upd_bf,   fr, kq, ks);
                bf16x8 as = ldA128(slots_bf, fr, kq, ks);
                gi0 = MFMA16(au, ldW128(Wih_bf,       w * 16 + fr, ks, kq), gi0);
                gi1 = MFMA16(au, ldW128(Wih_bf, 128 + w * 16 + fr, ks, kq), gi1);
                gi2 = MFMA16(au, ldW128(Wih_bf, 256 + w * 16 + fr, ks, kq), gi2);
                gh0 = MFMA16(as, ldW128(Whh_bf,       w * 16 + fr, ks, kq), gh0);
                gh1 = MFMA16(as, ldW128(Whh_bf, 128 + w * 16 + fr, ks, kq), gh1);
                gh2 = MFMA16(as, ldW128(Whh_bf, 256 + w * 16 + fr, ks, kq), gh2);
            }
            if (kq < 2) {
                int d = w * 16 + fr;
                float bi0 = bih[d], bi1 = bih[128 + d], bi2 = bih[256 + d];
                float bh0 = bhh[d], bh1 = bhh[128 + d], bh2 = bhh[256 + d];
                #pragma unroll
                for (int r = 0; r < 4; ++r) {
                    int m = kq * 4 + r;
                    float rr = 1.f / (1.f + expf(-((gi0[r] + bi0) + (gh0[r] + bh0))));
                    float zz = 1.f / (1.f + expf(-((gi1[r] + bi1) + (gh1[r] + bh1))));
                    float nn = tanhf((gi2[r] + bi2) + rr * (gh2[r] + bh2));
                    float h = slots[m][d];
                    slots[m][d] = (1.f - zz) * nn + zz * h;
                }
            }
        }
        __syncthreads();
        // (h) LN_out -> sln_bf
        {
            float x0 = slots[w][lane], x1 = slots[w][lane + 64];
            float s  = wave_red_sum64(x0 + x1);
            float s2 = wave_red_sum64(x0 * x0 + x1 * x1);
            float m = s * 0.0078125f;
            float rs = rsqrtf(s2 * 0.0078125f - m * m + 1e-5f);
            sln_bf[swz128(w, lane)]      = f2bf((x0 - m) * rs * log_[lane]      + lob[lane]);
            sln_bf[swz128(w, lane + 64)] = f2bf((x1 - m) * rs * log_[lane + 64] + lob[lane + 64]);
        }
        __syncthreads();
        // (i) MLP1 -> h_bf
        {
            f32x4 acc = {0.f, 0.f, 0.f, 0.f};
            #pragma unroll
            for (int ks = 0; ks < 4; ++ks)
                acc = MFMA16(ldA128(sln_bf, fr, kq, ks), ldW128(W1_bf, w * 16 + fr, ks, kq), acc);
            if (kq < 2) {
                float b1 = mb1[w * 16 + fr];
                #pragma unroll
                for (int r = 0; r < 4; ++r)
                    h_bf[swz128(kq * 4 + r, w * 16 + fr)] = f2bf(fmaxf(acc[r] + b1, 0.f));
            }
        }
        __syncthreads();
        // (j) MLP2 residual -> slots, slots_bf
        {
            f32x4 acc = {0.f, 0.f, 0.f, 0.f};
            #pragma unroll
            for (int ks = 0; ks < 4; ++ks)
                acc = MFMA16(ldA128(h_bf, fr, kq, ks), ldW128(W2_bf, w * 16 + fr, ks, kq), acc);
            if (kq < 2) {
                float b2 = mb2[w * 16 + fr];
                #pragma unroll
                for (int r = 0; r < 4; ++r) {
                    int m = kq * 4 + r, d = w * 16 + fr;
                    float v = slots[m][d] + acc[r] + b2;
                    slots[m][d] = v;
                    slots_bf[swz128(m, d)] = f2bf(v);
                }
            }
        }
        __syncthreads();
    }
    // epilogue: raw slots out + fused LN_dec -> sdec_bf
    {
        float x0 = slots[w][lane], x1 = slots[w][lane + 64];
        out_slots[(size_t)b * 1024 + w * 128 + lane]      = x0;
        out_slots[(size_t)b * 1024 + w * 128 + lane + 64] = x1;
        float s  = wave_red_sum64(x0 + x1);
        float s2 = wave_red_sum64(x0 * x0 + x1 * x1);
        float m = s * 0.0078125f;
        float rs = rsqrtf(s2 * 0.0078125f - m * m + 1e-5f);
        sdec_bf[((size_t)b * 8 + w) * 128 + lane]      = f2bf((x0 - m) * rs * ldg_[lane]      + ldb_[lane]);
        sdec_bf[((size_t)b * 8 + w) * 128 + lane + 64] = f2bf((x1 - m) * rs * ldg_[lane + 64] + ldb_[lane + 64]);
    }
}

// ---------------- K5: fused recon + squared-error + last-block final reduce ----------------
__global__ __launch_bounds__(256) void recon_loss_k(
    const float* __restrict__ feats, const float* __restrict__ attnv,
    const float* __restrict__ sf, float* __restrict__ partials,
    unsigned int* __restrict__ counter, float* __restrict__ out_loss) {

    __shared__ float sfl[8][768];
    __shared__ float al[49][8];
    __shared__ float wred[4];
    __shared__ bool is_last;
    int b = blockIdx.x >> 2, qd = blockIdx.x & 3, t = threadIdx.x;
    for (int idx = t; idx < 8 * 768; idx += 256)
        ((float*)sfl)[idx] = sf[(size_t)b * 8 * 768 + idx];
    int n0 = qd * 49;
    for (int idx = t; idx < 49 * 8; idx += 256)
        ((float*)al)[idx] = attnv[((size_t)b * N_ + n0) * 8 + idx];
    __syncthreads();
    float acc = 0.f;
    for (int nl = 0; nl < 49; ++nl) {
        float a0 = al[nl][0], a1 = al[nl][1], a2 = al[nl][2], a3 = al[nl][3];
        float a4 = al[nl][4], a5 = al[nl][5], a6 = al[nl][6], a7 = al[nl][7];
        const float* frow = feats + ((size_t)(b * N_ + n0 + nl)) * E_;
        for (int c = t; c < E_; c += 256) {
            float r = sfl[0][c]*a0 + sfl[1][c]*a1 + sfl[2][c]*a2 + sfl[3][c]*a3
                    + sfl[4][c]*a4 + sfl[5][c]*a5 + sfl[6][c]*a6 + sfl[7][c]*a7;
            float d = r - frow[c];
            acc += d * d;
        }
    }
    acc = wave_red_sum64(acc);
    int lane = t & 63, w = t >> 6;
    if (lane == 0) wred[w] = acc;
    __syncthreads();
    if (t == 0) {
        partials[b * 4 + qd] = wred[0] + wred[1] + wred[2] + wred[3];
        __threadfence();                       // partial visible device-wide
        unsigned int prev = atomicAdd(counter, 1u);
        is_last = (prev == 511u);
    }
    __syncthreads();
    if (is_last) {
        __threadfence();                       // acquire all partials
        float v = partials[t] + partials[t + 256];
        v = wave_red_sum64(v);
        if (lane == 0) wred[w] = v;
        __syncthreads();
        if (t == 0) {
            out_loss[0] = (wred[0] + wred[1] + wred[2] + wred[3]) / (float)(B_ * N_ * E_);
            *counter = 0;                      // self-clean for graph replays
        }
    }
}

// ---------------- launch ----------------
extern "C" void kernel_launch(void* const* d_in, const int* in_sizes, int n_in,
                              void* d_out, int out_size, void* d_ws, size_t ws_size,
                              hipStream_t stream) {
    (void)in_sizes; (void)n_in; (void)out_size; (void)ws_size;
    const float* feats     = (const float*)d_in[0];
    const float* noise     = (const float*)d_in[1];
    const float* ln_in_g   = (const float*)d_in[2];
    const float* ln_in_b   = (const float*)d_in[3];
    const float* ln_slot_g = (const float*)d_in[4];
    const float* ln_slot_b = (const float*)d_in[5];
    const float* ln_out_g  = (const float*)d_in[6];
    const float* ln_out_b  = (const float*)d_in[7];
    const float* ln_dec_g  = (const float*)d_in[8];
    const float* ln_dec_b  = (const float*)d_in[9];
    const float* mu        = (const float*)d_in[10];
    const float* log_sigma = (const float*)d_in[11];
    const float* Wk        = (const float*)d_in[12];
    const float* Wq        = (const float*)d_in[13];
    const float* Wv        = (const float*)d_in[14];
    const float* W_ih      = (const float*)d_in[15];
    const float* W_hh      = (const float*)d_in[16];
    const float* b_ih      = (const float*)d_in[17];
    const float* b_hh      = (const float*)d_in[18];
    const float* mlp_W1    = (const float*)d_in[19];
    const float* mlp_b1    = (const float*)d_in[20];
    const float* mlp_W2    = (const float*)d_in[21];
    const float* mlp_b2    = (const float*)d_in[22];
    const float* dec_W1    = (const float*)d_in[23];
    const float* dec_b1    = (const float*)d_in[24];
    const float* dec_W2    = (const float*)d_in[25];
    const float* dec_b2    = (const float*)d_in[26];
    const float* dec_W3    = (const float*)d_in[27];
    const float* dec_b3    = (const float*)d_in[28];

    float* ws    = (float*)d_ws;
    float* parts = ws + OFF_PART;                       // 512 floats
    unsigned int* counter = (unsigned int*)(ws + OFF_PART + 512);
    unsigned short* sdec_bf = (unsigned short*)(ws + OFF_SDEC);   // [1024][128]
    unsigned short* Wbase   = (unsigned short*)(ws + OFF_WBF);
    unsigned short* Wv_bf   = Wbase;              // [128][768]
    unsigned short* Wih_bf  = Wbase + 98304;      // [384][128]
    unsigned short* Whh_bf  = Wbase + 147456;     // [384][128]
    unsigned short* W1_bf   = Wbase + 196608;     // [128][128]
    unsigned short* W2_bf   = Wbase + 212992;     // [128][128]
    unsigned short* dW1_bf  = Wbase + 229376;     // [256][128]
    unsigned short* dW2_bf  = Wbase + 262144;     // [768][256]
    unsigned short* dW3_bf  = Wbase + 458752;     // [768][768]
    unsigned short* WMt     = Wbase + 1048576;    // [128][768]
    unsigned short* kpq_bf  = (unsigned short*)(ws + OFF_KPBF);   // [128][208][128]
    unsigned short* vpT_bf  = (unsigned short*)(ws + OFF_VPTBF);  // [128][128][224]
    unsigned short* Abf     = (unsigned short*)(ws + OFF_ABF);    // [25088][768]
    // decoder intermediates alias the Abf region (dead after mfma_proj_k)
    float*          sf      = ws + OFF_ABF;                        // [1024][768] fp32
    unsigned short* h1_bf   = (unsigned short*)(ws + OFF_ABF + 786432);           // [1024][256]
    unsigned short* h2_bf   = (unsigned short*)(ws + OFF_ABF + 786432 + 131072);  // [1024][768]

    float* out_slots = (float*)d_out;               // [128,8,128]
    float* out_attn  = out_slots + 131072;          // [128,196,8]
    float* out_loss  = out_slots + 331776;          // scalar

    WCArgs wa;
    wa.m[0] = {Wv,     Wv_bf,  0};     // 48 blocks
    wa.m[1] = {W_ih,   Wih_bf, 48};    // 24
    wa.m[2] = {W_hh,   Whh_bf, 72};    // 24
    wa.m[3] = {mlp_W1, W1_bf,  96};    // 8
    wa.m[4] = {mlp_W2, W2_bf,  104};   // 8
    wa.m[5] = {dec_W1, dW1_bf, 112};   // 16
    wa.m[6] = {dec_W2, dW2_bf, 128};   // 96
    wa.m[7] = {dec_W3, dW3_bf, 224};   // 288 -> 512 total conv
    // blocks: 6 wfold + 512 conv + 640 padzero = 1158 (also resets counter)
    prep_all_k<<<1158, 256, 0, stream>>>(Wq, Wk, WMt, wa, kpq_bf, vpT_bf, counter);

    ln_bf16_k<<<BNR / 4, 256, 0, stream>>>(feats, ln_in_g, ln_in_b, Abf);
    mfma_proj_k<<<BNR / 128, 512, 0, stream>>>(Abf, WMt, Wv_bf, kpq_bf, vpT_bf);

    slot_iter_mfma<<<B_, 512, 0, stream>>>(noise, ln_slot_g, ln_slot_b, ln_out_g, ln_out_b,
                                           ln_dec_g, ln_dec_b, mu, log_sigma,
                                           Wih_bf, Whh_bf, b_ih, b_hh,
                                           W1_bf, mlp_b1, W2_bf, mlp_b2, kpq_bf, vpT_bf,
                                           out_slots, out_attn, sdec_bf);

    // decoder: 3 bf16 MFMA GEMMs over M=1024
    mfma_mlp_k<128, 0><<<dim3(8, 2), 256, 0, stream>>>(sdec_bf, dW1_bf, dec_b1, h1_bf, nullptr, 256);
    mfma_mlp_k<256, 0><<<dim3(8, 6), 256, 0, stream>>>(h1_bf,  dW2_bf, dec_b2, h2_bf, nullptr, 768);
    mfma_mlp_k<768, 1><<<dim3(8, 6), 256, 0, stream>>>(h2_bf,  dW3_bf, dec_b3, nullptr, sf, 768);

    recon_loss_k<<<512, 256, 0, stream>>>(feats, out_attn, sf, parts, counter, out_loss);
}

// Round 17
// 197.180 us; speedup vs baseline: 1.0464x; 1.0464x over previous
//
#include <hip/hip_runtime.h>
#include <hip/hip_bf16.h>
#include <math.h>

// ---------------- problem constants ----------------
#define B_    128
#define N_    196
#define E_    768
#define K_    8
#define D_    128
#define BNR   (B_*N_)        // 25088 rows
#define ITERS 5

// ws layout (float units)
#define OFF_PART   0          // 512
#define OFF_SDEC   512        // ushort[1024*128] = 65536 floats
#define OFF_WBF    66048      // ushort region (incl. WMt)
#define OFF_KPBF   639488     // ushort[128*208*128]
#define OFF_VPTBF  2343424    // ushort[128*128*224]
#define OFF_ABF    4178432    // ushort[25088*768] (aliased by sf/h1/h2 after proj)

typedef __attribute__((ext_vector_type(8))) short bf16x8;
typedef __attribute__((ext_vector_type(4))) float f32x4;

#define MFMA16(a, b, c) __builtin_amdgcn_mfma_f32_16x16x32_bf16(a, b, c, 0, 0, 0)

__device__ __forceinline__ float wave_red_sum64(float v) {
    #pragma unroll
    for (int o = 32; o > 0; o >>= 1) v += __shfl_xor(v, o);
    return v;
}

__device__ __forceinline__ unsigned short f2bf(float v) {
    union { float f; unsigned int u; } c; c.f = v;
    unsigned int u = c.u + 0x7fffu + ((c.u >> 16) & 1u);  // RNE
    return (unsigned short)(u >> 16);
}

__device__ __forceinline__ void gl_lds16(const void* g, void* l) {
    __builtin_amdgcn_global_load_lds(
        (const __attribute__((address_space(1))) unsigned int*)g,
        (__attribute__((address_space(3))) unsigned int*)l, 16, 0, 0);
}

// chunk-XOR swizzled LDS addressing (8-bf16 = 16B chunks)
__device__ __forceinline__ int swz128(int row, int j) {
    return row * 128 + ((((j >> 3) ^ (row & 7))) << 3) + (j & 7);
}
__device__ __forceinline__ int swz256(int row, int j) {
    return row * 256 + ((((j >> 3) ^ (row & 7))) << 3) + (j & 7);
}
__device__ __forceinline__ bf16x8 ldA128(const unsigned short* base, int row, int kq, int ks) {
    int ch = (ks * 4 + kq) ^ (row & 7);
    return *(const bf16x8*)(base + row * 128 + ch * 8);
}
__device__ __forceinline__ bf16x8 ldA256(const unsigned short* base, int row, int kq, int ks) {
    int ch = (ks * 4 + kq) ^ (row & 7);
    return *(const bf16x8*)(base + row * 256 + ch * 8);
}
__device__ __forceinline__ bf16x8 ldW128(const unsigned short* W, int row, int ks, int kq) {
    return *(const bf16x8*)(W + (size_t)row * 128 + ks * 32 + kq * 8);
}

// ---------------- K0: merged prep: wfold (blocks 0-5) + conversions (6-517) + padzero (518-1157) ----------------
struct WCEnt { const float* s; unsigned short* d; int t0; };
struct WCArgs { WCEnt m[8]; };

__global__ __launch_bounds__(256) void prep_all_k(const float* __restrict__ Wq,
                                                  const float* __restrict__ Wk,
                                                  unsigned short* __restrict__ WMt,
                                                  WCArgs a,
                                                  unsigned short* __restrict__ kpb,
                                                  unsigned short* __restrict__ vpt) {
    __shared__ __align__(16) unsigned short Aq[128 * 128];
    __shared__ __align__(16) unsigned short Bk[128 * 128];
    int bid = blockIdx.x;
    int t = threadIdx.x;
    if (bid < 6) {
        const float s = 0.08838834764831845f;  // 128^-0.5
        int e0 = bid * 128;
        for (int idx = t; idx < 16384; idx += 256) {
            int o = idx >> 7, c = idx & 127;
            Aq[swz128(c, o)] = f2bf(Wq[(size_t)o * 128 + c]);           // Aq[i][o] = Wq[o][i]
            Bk[swz128(c, o)] = f2bf(Wk[(size_t)o * 768 + e0 + c] * s);  // Bk[e][o] = s*Wk[o][e]
        }
        __syncthreads();
        int w = t >> 6, l = t & 63;
        int wr = w >> 1, wc = w & 1, fr = l & 15, kq = l >> 4;
        f32x4 acc[4][4];
        #pragma unroll
        for (int mi = 0; mi < 4; ++mi)
            #pragma unroll
            for (int nj = 0; nj < 4; ++nj) acc[mi][nj] = (f32x4){0.f, 0.f, 0.f, 0.f};
        #pragma unroll
        for (int ks = 0; ks < 4; ++ks) {
            bf16x8 af[4], bfr[4];
            #pragma unroll
            for (int mi = 0; mi < 4; ++mi) af[mi] = ldA128(Aq, wr * 64 + mi * 16 + fr, kq, ks);
            #pragma unroll
            for (int nj = 0; nj < 4; ++nj) bfr[nj] = ldA128(Bk, wc * 64 + nj * 16 + fr, kq, ks);
            #pragma unroll
            for (int mi = 0; mi < 4; ++mi)
                #pragma unroll
                for (int nj = 0; nj < 4; ++nj)
                    acc[mi][nj] = MFMA16(af[mi], bfr[nj], acc[mi][nj]);
        }
        #pragma unroll
        for (int mi = 0; mi < 4; ++mi) {
            int rowbase = wr * 64 + mi * 16 + kq * 4;
            #pragma unroll
            for (int nj = 0; nj < 4; ++nj) {
                int col = e0 + wc * 64 + nj * 16 + fr;
                #pragma unroll
                for (int r = 0; r < 4; ++r)
                    WMt[(size_t)(rowbase + r) * 768 + col] = f2bf(acc[mi][nj][r]);
            }
        }
    } else if (bid < 518) {
        int cbid = bid - 6, i = 0;
        #pragma unroll
        for (int j = 1; j < 8; ++j) if (cbid >= a.m[j].t0) i = j;
        int off = (cbid - a.m[i].t0) * 2048 + t * 8;
        const float* s = a.m[i].s + off;
        unsigned short* d = a.m[i].d + off;
        float4 v0 = *(const float4*)s, v1 = *(const float4*)(s + 4);
        ushort4 o0, o1;
        o0.x = f2bf(v0.x); o0.y = f2bf(v0.y); o0.z = f2bf(v0.z); o0.w = f2bf(v0.w);
        o1.x = f2bf(v1.x); o1.y = f2bf(v1.y); o1.z = f2bf(v1.z); o1.w = f2bf(v1.w);
        *(ushort4*)d = o0; *(ushort4*)(d + 4) = o1;
    } else {
        int i = (bid - 518) * 256 + t;   // ushort4 index, 163840 total
        ushort4 z = {0, 0, 0, 0};
        if (i < 49152) {                 // kp pads: 128 b x 12 rows x 128
            int q = i * 4;
            int b = q / 1536, off = q - b * 1536;
            *(ushort4*)(kpb + ((size_t)b * 208 + 196) * 128 + off) = z;
        } else {                          // vpT pads: per (b,d) cols 196..223
            int c = i - 49152;            // 0..114687
            int bd = c / 7, cc = c - bd * 7;
            *(ushort4*)(vpt + (size_t)bd * 224 + 196 + cc * 4) = z;
        }
    }
}

// ---------------- K1: one-pass LayerNorm(features) -> bf16 ----------------
__global__ __launch_bounds__(256) void ln_bf16_k(const float* __restrict__ f,
                                                 const float* __restrict__ g,
                                                 const float* __restrict__ bv,
                                                 unsigned short* __restrict__ out) {
    int wid = blockIdx.x * 4 + (threadIdx.x >> 6);   // one wave per row
    int lane = threadIdx.x & 63;
    const float* row = f + (size_t)wid * E_;
    float4 x[3];
    float s = 0.f, s2 = 0.f;
    #pragma unroll
    for (int c = 0; c < 3; ++c) {
        x[c] = *(const float4*)(row + c * 256 + lane * 4);
        s  += x[c].x + x[c].y + x[c].z + x[c].w;
        s2 += x[c].x * x[c].x + x[c].y * x[c].y + x[c].z * x[c].z + x[c].w * x[c].w;
    }
    s  = wave_red_sum64(s);
    s2 = wave_red_sum64(s2);
    float m = s * (1.f / E_);
    float rs = rsqrtf(s2 * (1.f / E_) - m * m + 1e-5f);
    #pragma unroll
    for (int c = 0; c < 3; ++c) {
        float4 g4 = *(const float4*)(g + c * 256 + lane * 4);
        float4 b4 = *(const float4*)(bv + c * 256 + lane * 4);
        ushort4 o;
        o.x = f2bf((x[c].x - m) * rs * g4.x + b4.x);
        o.y = f2bf((x[c].y - m) * rs * g4.y + b4.y);
        o.z = f2bf((x[c].z - m) * rs * g4.z + b4.z);
        o.w = f2bf((x[c].w - m) * rs * g4.w + b4.w);
        *(ushort4*)(out + (size_t)wid * E_ + c * 256 + lane * 4) = o;
    }
}

// ---------------- K2: dual-output bf16 MFMA GEMM: kpq (row-major) + vpT (LDS-transposed) ----------------
__global__ __launch_bounds__(512) void mfma_proj_k(const unsigned short* __restrict__ Abf,
                                                   const unsigned short* __restrict__ WMt,
                                                   const unsigned short* __restrict__ Wv_bf,
                                                   unsigned short* __restrict__ kpq_bf,
                                                   unsigned short* __restrict__ vpT_bf) {
    __shared__ __align__(16) unsigned short As[128 * 64];   // 1024 chunks
    __shared__ __align__(16) unsigned short Bs[256 * 64];   // 2048 chunks; reused as transpose buf
    const int t = threadIdx.x, w = t >> 6, l = t & 63;
    const int m0 = blockIdx.x * 128;
    const int wr = w >> 2, wc = w & 3;
    const int fr = l & 15, kq = l >> 4;
    f32x4 acc[4][4];
    #pragma unroll
    for (int mi = 0; mi < 4; ++mi)
        #pragma unroll
        for (int nj = 0; nj < 4; ++nj) acc[mi][nj] = (f32x4){0.f, 0.f, 0.f, 0.f};

    for (int ks = 0; ks < E_; ks += 64) {
        __syncthreads();
        #pragma unroll
        for (int j = 0; j < 2; ++j) {      // A: 1024 chunks
            int ci = j * 512 + (w << 6) + l;
            int r = ci >> 3, c = ci & 7, cg = c ^ (r & 7);
            gl_lds16(Abf + (size_t)(m0 + r) * E_ + ks + cg * 8,
                     As + (size_t)(j * 512 + (w << 6)) * 8);
        }
        #pragma unroll
        for (int j = 0; j < 4; ++j) {      // B: 2048 chunks (256 rows)
            int ci = j * 512 + (w << 6) + l;
            int r = ci >> 3, c = ci & 7, cg = c ^ (r & 7);
            const unsigned short* src = (r < 128)
                ? WMt   + (size_t)r * E_ + ks + cg * 8
                : Wv_bf + (size_t)(r - 128) * E_ + ks + cg * 8;
            gl_lds16(src, Bs + (size_t)(j * 512 + (w << 6)) * 8);
        }
        __syncthreads();
        #pragma unroll
        for (int kk = 0; kk < 2; ++kk) {
            bf16x8 af[4], bfr[4];
            #pragma unroll
            for (int mi = 0; mi < 4; ++mi) {
                int rr = wr * 64 + mi * 16 + fr;
                af[mi] = *(const bf16x8*)(As + rr * 64 + (((kk * 4 + kq) ^ (rr & 7))) * 8);
            }
            #pragma unroll
            for (int nj = 0; nj < 4; ++nj) {
                int rr = wc * 64 + nj * 16 + fr;
                bfr[nj] = *(const bf16x8*)(Bs + rr * 64 + (((kk * 4 + kq) ^ (rr & 7))) * 8);
            }
            #pragma unroll
            for (int mi = 0; mi < 4; ++mi)
                #pragma unroll
                for (int nj = 0; nj < 4; ++nj)
                    acc[mi][nj] = MFMA16(af[mi], bfr[nj], acc[mi][nj]);
        }
    }
    __syncthreads();   // all LDS MFMA reads complete before Bs reuse
    if (wc < 2) {
        // kpq quadrants: row-major padded per-batch writes
        #pragma unroll
        for (int mi = 0; mi < 4; ++mi) {
            int rowbase = m0 + wr * 64 + mi * 16 + kq * 4;
            #pragma unroll
            for (int r = 0; r < 4; ++r) {
                int m = rowbase + r;
                int b = m / 196, rr = m - b * 196;
                size_t o = ((size_t)b * 208 + rr) * 128;
                #pragma unroll
                for (int nj = 0; nj < 4; ++nj)
                    kpq_bf[o + wc * 64 + nj * 16 + fr] = f2bf(acc[mi][nj][r]);
            }
        }
    } else {
        // vp quadrants: transpose into Bs[d][tok] with XOR chunk swizzle
        int dbase = (wc - 2) * 64;
        #pragma unroll
        for (int mi = 0; mi < 4; ++mi) {
            int tok = wr * 64 + mi * 16 + kq * 4;
            #pragma unroll
            for (int nj = 0; nj < 4; ++nj) {
                int d = dbase + nj * 16 + fr;
                ushort4 pk;
                pk.x = f2bf(acc[mi][nj][0]); pk.y = f2bf(acc[mi][nj][1]);
                pk.z = f2bf(acc[mi][nj][2]); pk.w = f2bf(acc[mi][nj][3]);
                *(ushort4*)(Bs + d * 128 + (tok ^ ((d & 7) << 3))) = pk;
            }
        }
    }
    __syncthreads();
    // coalesced vpT store: thread t -> d = t>>2, m-range (t&3)*32..+32
    {
        int d = t >> 2, mg = t & 3;
        #pragma unroll
        for (int sc = 0; sc < 4; ++sc) {
            int mstart = mg * 32 + sc * 8;
            int cm = mstart >> 3;
            const unsigned short* src = Bs + d * 128 + ((cm ^ (d & 7)) << 3);
            int g0 = m0 + mstart;
            int b0 = g0 / 196, rr0 = g0 - b0 * 196;
            int b7 = (g0 + 7) / 196;
            if (b0 == b7) {
                unsigned short* dst = vpT_bf + ((size_t)b0 * 128 + d) * 224 + rr0;
                *(ushort4*)(dst)     = *(const ushort4*)(src);
                *(ushort4*)(dst + 4) = *(const ushort4*)(src + 4);
            } else {
                #pragma unroll
                for (int e = 0; e < 8; ++e) {
                    int g = g0 + e;
                    int bb = g / 196, rr = g - bb * 196;
                    vpT_bf[((size_t)bb * 128 + d) * 224 + rr] = src[e];
                }
            }
        }
    }
}

// ---------------- K2b: generic MLP-layer MFMA GEMM (R6-proven staging) ----------------
template<int KTOT, int EPI>
__global__ __launch_bounds__(256) void mfma_mlp_k(const unsigned short* __restrict__ A,
                                                  const unsigned short* __restrict__ Bw,
                                                  const float* __restrict__ bias,
                                                  unsigned short* __restrict__ out_bf,
                                                  float* __restrict__ out_f,
                                                  int ldN) {
    __shared__ __align__(16) unsigned short As[128 * 64];
    __shared__ __align__(16) unsigned short Bs[128 * 64];
    const int t = threadIdx.x, w = t >> 6, l = t & 63;
    const int m0 = blockIdx.x * 128;
    const int n0 = blockIdx.y * 128;
    const int wr = w >> 1, wc = w & 1;
    const int fr = l & 15, kq = l >> 4;
    f32x4 acc[4][4];
    #pragma unroll
    for (int mi = 0; mi < 4; ++mi)
        #pragma unroll
        for (int nj = 0; nj < 4; ++nj) acc[mi][nj] = (f32x4){0.f, 0.f, 0.f, 0.f};

    for (int ks = 0; ks < KTOT; ks += 64) {
        __syncthreads();
        #pragma unroll
        for (int j = 0; j < 4; ++j) {
            int ci = (w << 8) + (j << 6) + l;
            int r = ci >> 3, c = ci & 7;
            int cg = c ^ (r & 7);
            gl_lds16(A  + (size_t)(m0 + r) * KTOT + ks + cg * 8,
                     As + (size_t)((w << 8) + (j << 6)) * 8);
            gl_lds16(Bw + (size_t)(n0 + r) * KTOT + ks + cg * 8,
                     Bs + (size_t)((w << 8) + (j << 6)) * 8);
        }
        __syncthreads();
        #pragma unroll
        for (int kk = 0; kk < 2; ++kk) {
            bf16x8 af[4], bfr[4];
            int ch = (kk * 4 + kq) ^ (fr & 7);
            #pragma unroll
            for (int mi = 0; mi < 4; ++mi)
                af[mi] = *(const bf16x8*)(As + (wr * 64 + mi * 16 + fr) * 64 + ch * 8);
            #pragma unroll
            for (int nj = 0; nj < 4; ++nj)
                bfr[nj] = *(const bf16x8*)(Bs + (wc * 64 + nj * 16 + fr) * 64 + ch * 8);
            #pragma unroll
            for (int mi = 0; mi < 4; ++mi)
                #pragma unroll
                for (int nj = 0; nj < 4; ++nj)
                    acc[mi][nj] = MFMA16(af[mi], bfr[nj], acc[mi][nj]);
        }
    }
    #pragma unroll
    for (int mi = 0; mi < 4; ++mi) {
        int rowbase = m0 + wr * 64 + mi * 16 + kq * 4;
        #pragma unroll
        for (int nj = 0; nj < 4; ++nj) {
            int col = n0 + wc * 64 + nj * 16 + fr;
            float bc = bias[col];
            #pragma unroll
            for (int r = 0; r < 4; ++r) {
                float v = acc[mi][nj][r] + bc;
                if (EPI == 0)
                    out_bf[(size_t)(rowbase + r) * ldN + col] = f2bf(fmaxf(v, 0.f));
                else
                    out_f[(size_t)(rowbase + r) * ldN + col] = v;
            }
        }
    }
}

// ---------------- K3: persistent per-batch slot-attention iterations (MFMA) ----------------
// R10/R15 8-phase structure (proven 64 us). No register hoists: hipcc caps
// 512-thread kernels at 128 VGPR and rematerializes/spills any hoist (R11/R12/R15).
__global__ __launch_bounds__(512) void slot_iter_mfma(
    const float* __restrict__ noise,
    const float* __restrict__ lsg, const float* __restrict__ lsb,
    const float* __restrict__ log_, const float* __restrict__ lob,
    const float* __restrict__ ldg_, const float* __restrict__ ldb_,
    const float* __restrict__ mup, const float* __restrict__ lsig,
    const unsigned short* __restrict__ Wih_bf,
    const unsigned short* __restrict__ Whh_bf,
    const float* __restrict__ bih, const float* __restrict__ bhh,
    const unsigned short* __restrict__ W1_bf, const float* __restrict__ mb1,
    const unsigned short* __restrict__ W2_bf, const float* __restrict__ mb2,
    const unsigned short* __restrict__ kpq_bf,
    const unsigned short* __restrict__ vpT_bf,
    float* __restrict__ out_slots, float* __restrict__ out_attn,
    unsigned short* __restrict__ sdec_bf) {

    __shared__ float slots[8][128];
    __shared__ float attn[208][9];
    __shared__ float colpart[8][8];
    __shared__ __align__(16) unsigned short sln_bf[2048];
    __shared__ __align__(16) unsigned short upd_bf[2048];
    __shared__ __align__(16) unsigned short slots_bf[2048];
    __shared__ __align__(16) unsigned short h_bf[2048];
    __shared__ __align__(16) unsigned short attnT_bf[4096];

    const int b = blockIdx.x, t = threadIdx.x;
    const int lane = t & 63, w = t >> 6;
    const int fr = lane & 15, kq = lane >> 4;

    for (int i = t; i < 2048; i += 512) {
        sln_bf[i] = 0; upd_bf[i] = 0; slots_bf[i] = 0; h_bf[i] = 0;
    }
    for (int i = t; i < 4096; i += 512) attnT_bf[i] = 0;

    for (int idx = t; idx < 1024; idx += 512) {
        int k = idx >> 7, d = idx & 127;
        float v = noise[(size_t)b * 1024 + idx] * expf(lsig[d]) + mup[d];
        slots[k][d] = v;
        slots_bf[swz128(k, d)] = f2bf(v);
    }
    __syncthreads();

    for (int it = 0; it < ITERS; ++it) {
        bool last = (it == ITERS - 1);
        // (a) LN_slot -> sln_bf (wave w owns slot w)
        {
            float x0 = slots[w][lane], x1 = slots[w][lane + 64];
            float s  = wave_red_sum64(x0 + x1);
            float s2 = wave_red_sum64(x0 * x0 + x1 * x1);
            float m = s * 0.0078125f;
            float rs = rsqrtf(s2 * 0.0078125f - m * m + 1e-5f);
            sln_bf[swz128(w, lane)]      = f2bf((x0 - m) * rs * lsg[lane]      + lsb[lane]);
            sln_bf[swz128(w, lane + 64)] = f2bf((x1 - m) * rs * lsg[lane + 64] + lsb[lane + 64]);
        }
        __syncthreads();
        // (c) logits = kpq @ sln^T, softmax over slots -> attn LDS + colpart
        {
            float cp = 0.f;
            #pragma unroll
            for (int p = 0; p < 2; ++p) {
                int tt = w + p * 8;
                if (tt <= 12) {
                    f32x4 acc = {0.f, 0.f, 0.f, 0.f};
                    const unsigned short* kpr = kpq_bf + ((size_t)b * 208 + tt * 16 + fr) * 128;
                    #pragma unroll
                    for (int ks = 0; ks < 4; ++ks)
                        acc = MFMA16(*(const bf16x8*)(kpr + ks * 32 + kq * 8),
                                     ldA128(sln_bf, fr, kq, ks), acc);
                    #pragma unroll
                    for (int r = 0; r < 4; ++r) {
                        float v = acc[r];
                        float mx = fmaxf(v, __shfl_xor(v, 1));
                        mx = fmaxf(mx, __shfl_xor(mx, 2));
                        mx = fmaxf(mx, __shfl_xor(mx, 4));
                        float e = expf(v - mx);
                        float sm = e;
                        sm += __shfl_xor(sm, 1); sm += __shfl_xor(sm, 2); sm += __shfl_xor(sm, 4);
                        float a = e / sm;
                        int tok = tt * 16 + kq * 4 + r;
                        bool valid = (tok < 196);
                        if (fr < 8 && valid) attn[tok][fr] = a;
                        cp += valid ? a : 0.f;
                    }
                }
            }
            cp += __shfl_xor(cp, 16);
            cp += __shfl_xor(cp, 32);
            if (lane < 8) colpart[w][lane] = cp;
        }
        __syncthreads();
        // (e) normalize over tokens -> attnT_bf (+ out_attn last iter)
        {
            int k = t & 7;
            float cs = colpart[0][k] + colpart[1][k] + colpart[2][k] + colpart[3][k]
                     + colpart[4][k] + colpart[5][k] + colpart[6][k] + colpart[7][k]
                     + 196.0f * 1e-8f;
            float inv = 1.f / cs;
            for (int idx = t; idx < 1568; idx += 512) {
                int n = idx >> 3;
                float raw = attn[n][k];
                attnT_bf[swz256(k, n)] = f2bf((raw + 1e-8f) * inv);
                if (last) out_attn[((size_t)b * 196 + n) * 8 + k] = raw;
            }
        }
        __syncthreads();
        // (f) updates = attn_norm^T @ v -> upd_bf
        {
            f32x4 acc = {0.f, 0.f, 0.f, 0.f};
            const unsigned short* vpr = vpT_bf + ((size_t)b * 128 + w * 16 + fr) * 224;
            #pragma unroll
            for (int ks = 0; ks < 7; ++ks)
                acc = MFMA16(ldA256(attnT_bf, fr, kq, ks),
                             *(const bf16x8*)(vpr + ks * 32 + kq * 8), acc);
            if (kq < 2) {
                #pragma unroll
                for (int r = 0; r < 4; ++r)
                    upd_bf[swz128(kq * 4 + r, w * 16 + fr)] = f2bf(acc[r]);
            }
        }
        __syncthreads();
        // (g) GRU
        {
            f32x4 gi0 = {0,0,0,0}, gi1 = {0,0,0,0}, gi2 = {0,0,0,0};
            f32x4 gh0 = {0,0,0,0}, gh1 = {0,0,0,0}, gh2 = {0,0,0,0};
            #pragma unroll
            for (int ks = 0; ks < 4; ++ks) {
                bf16x8 au = ldA128(upd_bf,   fr, kq, ks);
                bf16x8 as = ldA128(slots_bf, fr, kq, ks);
                gi0 = MFMA16(au, ldW128(Wih_bf,       w * 16 + fr, ks, kq), gi0);
                gi1 = MFMA16(au, ldW128(Wih_bf, 128 + w * 16 + fr, ks, kq), gi1);
                gi2 = MFMA16(au, ldW128(Wih_bf, 256 + w * 16 + fr, ks, kq), gi2);
                gh0 = MFMA16(as, ldW128(Whh_bf,       w * 16 + fr, ks, kq), gh0);
                gh1 = MFMA16(as, ldW128(Whh_bf, 128 + w * 16 + fr, ks, kq), gh1);
                gh2 = MFMA16(as, ldW128(Whh_bf, 256 + w * 16 + fr, ks, kq), gh2);
            }
            if (kq < 2) {
                int d = w * 16 + fr;
                float bi0 = bih[d], bi1 = bih[128 + d], bi2 = bih[256 + d];
                float bh0 = bhh[d], bh1 = bhh[128 + d], bh2 = bhh[256 + d];
                #pragma unroll
                for (int r = 0; r < 4; ++r) {
                    int m = kq * 4 + r;
                    float rr = 1.f / (1.f + expf(-((gi0[r] + bi0) + (gh0[r] + bh0))));
                    float zz = 1.f / (1.f + expf(-((gi1[r] + bi1) + (gh1[r] + bh1))));
                    float nn = tanhf((gi2[r] + bi2) + rr * (gh2[r] + bh2));
                    float h = slots[m][d];
                    slots[m][d] = (1.f - zz) * nn + zz * h;
                }
            }
        }
        __syncthreads();
        // (h) LN_out -> sln_bf
        {
            float x0 = slots[w][lane], x1 = slots[w][lane + 64];
            float s  = wave_red_sum64(x0 + x1);
            float s2 = wave_red_sum64(x0 * x0 + x1 * x1);
            float m = s * 0.0078125f;
            float rs = rsqrtf(s2 * 0.0078125f - m * m + 1e-5f);
            sln_bf[swz128(w, lane)]      = f2bf((x0 - m) * rs * log_[lane]      + lob[lane]);
            sln_bf[swz128(w, lane + 64)] = f2bf((x1 - m) * rs * log_[lane + 64] + lob[lane + 64]);
        }
        __syncthreads();
        // (i) MLP1 -> h_bf
        {
            f32x4 acc = {0.f, 0.f, 0.f, 0.f};
            #pragma unroll
            for (int ks = 0; ks < 4; ++ks)
                acc = MFMA16(ldA128(sln_bf, fr, kq, ks), ldW128(W1_bf, w * 16 + fr, ks, kq), acc);
            if (kq < 2) {
                float b1 = mb1[w * 16 + fr];
                #pragma unroll
                for (int r = 0; r < 4; ++r)
                    h_bf[swz128(kq * 4 + r, w * 16 + fr)] = f2bf(fmaxf(acc[r] + b1, 0.f));
            }
        }
        __syncthreads();
        // (j) MLP2 residual -> slots, slots_bf
        {
            f32x4 acc = {0.f, 0.f, 0.f, 0.f};
            #pragma unroll
            for (int ks = 0; ks < 4; ++ks)
                acc = MFMA16(ldA128(h_bf, fr, kq, ks), ldW128(W2_bf, w * 16 + fr, ks, kq), acc);
            if (kq < 2) {
                float b2 = mb2[w * 16 + fr];
                #pragma unroll
                for (int r = 0; r < 4; ++r) {
                    int m = kq * 4 + r, d = w * 16 + fr;
                    float v = slots[m][d] + acc[r] + b2;
                    slots[m][d] = v;
                    slots_bf[swz128(m, d)] = f2bf(v);
                }
            }
        }
        __syncthreads();
    }
    // epilogue: raw slots out + fused LN_dec -> sdec_bf
    {
        float x0 = slots[w][lane], x1 = slots[w][lane + 64];
        out_slots[(size_t)b * 1024 + w * 128 + lane]      = x0;
        out_slots[(size_t)b * 1024 + w * 128 + lane + 64] = x1;
        float s  = wave_red_sum64(x0 + x1);
        float s2 = wave_red_sum64(x0 * x0 + x1 * x1);
        float m = s * 0.0078125f;
        float rs = rsqrtf(s2 * 0.0078125f - m * m + 1e-5f);
        sdec_bf[((size_t)b * 8 + w) * 128 + lane]      = f2bf((x0 - m) * rs * ldg_[lane]      + ldb_[lane]);
        sdec_bf[((size_t)b * 8 + w) * 128 + lane + 64] = f2bf((x1 - m) * rs * ldg_[lane + 64] + ldb_[lane + 64]);
    }
}

// ---------------- K5: fused recon + squared-error partial sums ----------------
__global__ __launch_bounds__(256) void recon_loss_k(
    const float* __restrict__ feats, const float* __restrict__ attnv,
    const float* __restrict__ sf, float* __restrict__ partials) {

    __shared__ float sfl[8][768];
    __shared__ float al[49][8];
    __shared__ float wred[4];
    int b = blockIdx.x, qd = blockIdx.y, t = threadIdx.x;
    for (int idx = t; idx < 8 * 768; idx += 256)
        ((float*)sfl)[idx] = sf[(size_t)b * 8 * 768 + idx];
    int n0 = qd * 49;
    for (int idx = t; idx < 49 * 8; idx += 256)
        ((float*)al)[idx] = attnv[((size_t)b * N_ + n0) * 8 + idx];
    __syncthreads();
    float acc = 0.f;
    for (int nl = 0; nl < 49; ++nl) {
        float a0 = al[nl][0], a1 = al[nl][1], a2 = al[nl][2], a3 = al[nl][3];
        float a4 = al[nl][4], a5 = al[nl][5], a6 = al[nl][6], a7 = al[nl][7];
        const float* frow = feats + ((size_t)(b * N_ + n0 + nl)) * E_;
        for (int c = t; c < E_; c += 256) {
            float r = sfl[0][c]*a0 + sfl[1][c]*a1 + sfl[2][c]*a2 + sfl[3][c]*a3
                    + sfl[4][c]*a4 + sfl[5][c]*a5 + sfl[6][c]*a6 + sfl[7][c]*a7;
            float d = r - frow[c];
            acc += d * d;
        }
    }
    acc = wave_red_sum64(acc);
    int lane = t & 63, w = t >> 6;
    if (lane == 0) wred[w] = acc;
    __syncthreads();
    if (t == 0) partials[b * 4 + qd] = wred[0] + wred[1] + wred[2] + wred[3];
}

__global__ __launch_bounds__(512) void loss_final_k(const float* __restrict__ partials,
                                                    float* __restrict__ out) {
    __shared__ float wred[8];
    int t = threadIdx.x;
    float v = partials[t];
    v = wave_red_sum64(v);
    if ((t & 63) == 0) wred[t >> 6] = v;
    __syncthreads();
    if (t == 0) {
        float s = 0.f;
        #pragma unroll
        for (int i = 0; i < 8; ++i) s += wred[i];
        out[0] = s / (float)(B_ * N_ * E_);
    }
}

// ---------------- launch ----------------
extern "C" void kernel_launch(void* const* d_in, const int* in_sizes, int n_in,
                              void* d_out, int out_size, void* d_ws, size_t ws_size,
                              hipStream_t stream) {
    (void)in_sizes; (void)n_in; (void)out_size; (void)ws_size;
    const float* feats     = (const float*)d_in[0];
    const float* noise     = (const float*)d_in[1];
    const float* ln_in_g   = (const float*)d_in[2];
    const float* ln_in_b   = (const float*)d_in[3];
    const float* ln_slot_g = (const float*)d_in[4];
    const float* ln_slot_b = (const float*)d_in[5];
    const float* ln_out_g  = (const float*)d_in[6];
    const float* ln_out_b  = (const float*)d_in[7];
    const float* ln_dec_g  = (const float*)d_in[8];
    const float* ln_dec_b  = (const float*)d_in[9];
    const float* mu        = (const float*)d_in[10];
    const float* log_sigma = (const float*)d_in[11];
    const float* Wk        = (const float*)d_in[12];
    const float* Wq        = (const float*)d_in[13];
    const float* Wv        = (const float*)d_in[14];
    const float* W_ih      = (const float*)d_in[15];
    const float* W_hh      = (const float*)d_in[16];
    const float* b_ih      = (const float*)d_in[17];
    const float* b_hh      = (const float*)d_in[18];
    const float* mlp_W1    = (const float*)d_in[19];
    const float* mlp_b1    = (const float*)d_in[20];
    const float* mlp_W2    = (const float*)d_in[21];
    const float* mlp_b2    = (const float*)d_in[22];
    const float* dec_W1    = (const float*)d_in[23];
    const float* dec_b1    = (const float*)d_in[24];
    const float* dec_W2    = (const float*)d_in[25];
    const float* dec_b2    = (const float*)d_in[26];
    const float* dec_W3    = (const float*)d_in[27];
    const float* dec_b3    = (const float*)d_in[28];

    float* ws    = (float*)d_ws;
    float* parts = ws + OFF_PART;
    unsigned short* sdec_bf = (unsigned short*)(ws + OFF_SDEC);   // [1024][128]
    unsigned short* Wbase   = (unsigned short*)(ws + OFF_WBF);
    unsigned short* Wv_bf   = Wbase;              // [128][768]
    unsigned short* Wih_bf  = Wbase + 98304;      // [384][128]
    unsigned short* Whh_bf  = Wbase + 147456;     // [384][128]
    unsigned short* W1_bf   = Wbase + 196608;     // [128][128]
    unsigned short* W2_bf   = Wbase + 212992;     // [128][128]
    unsigned short* dW1_bf  = Wbase + 229376;     // [256][128]
    unsigned short* dW2_bf  = Wbase + 262144;     // [768][256]
    unsigned short* dW3_bf  = Wbase + 458752;     // [768][768]
    unsigned short* WMt     = Wbase + 1048576;    // [128][768]
    unsigned short* kpq_bf  = (unsigned short*)(ws + OFF_KPBF);   // [128][208][128]
    unsigned short* vpT_bf  = (unsigned short*)(ws + OFF_VPTBF);  // [128][128][224]
    unsigned short* Abf     = (unsigned short*)(ws + OFF_ABF);    // [25088][768]
    // decoder intermediates alias the Abf region (dead after mfma_proj_k)
    float*          sf      = ws + OFF_ABF;                        // [1024][768] fp32
    unsigned short* h1_bf   = (unsigned short*)(ws + OFF_ABF + 786432);           // [1024][256]
    unsigned short* h2_bf   = (unsigned short*)(ws + OFF_ABF + 786432 + 131072);  // [1024][768]

    float* out_slots = (float*)d_out;               // [128,8,128]
    float* out_attn  = out_slots + 131072;          // [128,196,8]
    float* out_loss  = out_slots + 331776;          // scalar

    WCArgs wa;
    wa.m[0] = {Wv,     Wv_bf,  0};     // 48 blocks
    wa.m[1] = {W_ih,   Wih_bf, 48};    // 24
    wa.m[2] = {W_hh,   Whh_bf, 72};    // 24
    wa.m[3] = {mlp_W1, W1_bf,  96};    // 8
    wa.m[4] = {mlp_W2, W2_bf,  104};   // 8
    wa.m[5] = {dec_W1, dW1_bf, 112};   // 16
    wa.m[6] = {dec_W2, dW2_bf, 128};   // 96
    wa.m[7] = {dec_W3, dW3_bf, 224};   // 288 -> 512 total conv
    // blocks: 6 wfold + 512 conv + 640 padzero = 1158
    prep_all_k<<<1158, 256, 0, stream>>>(Wq, Wk, WMt, wa, kpq_bf, vpT_bf);

    ln_bf16_k<<<BNR / 4, 256, 0, stream>>>(feats, ln_in_g, ln_in_b, Abf);
    mfma_proj_k<<<BNR / 128, 512, 0, stream>>>(Abf, WMt, Wv_bf, kpq_bf, vpT_bf);

    slot_iter_mfma<<<B_, 512, 0, stream>>>(noise, ln_slot_g, ln_slot_b, ln_out_g, ln_out_b,
                                           ln_dec_g, ln_dec_b, mu, log_sigma,
                                           Wih_bf, Whh_bf, b_ih, b_hh,
                                           W1_bf, mlp_b1, W2_bf, mlp_b2, kpq_bf, vpT_bf,
                                           out_slots, out_attn, sdec_bf);

    // decoder: 3 bf16 MFMA GEMMs over M=1024
    mfma_mlp_k<128, 0><<<dim3(8, 2), 256, 0, stream>>>(sdec_bf, dW1_bf, dec_b1, h1_bf, nullptr, 256);
    mfma_mlp_k<256, 0><<<dim3(8, 6), 256, 0, stream>>>(h1_bf,  dW2_bf, dec_b2, h2_bf, nullptr, 768);
    mfma_mlp_k<768, 1><<<dim3(8, 6), 256, 0, stream>>>(h2_bf,  dW3_bf, dec_b3, nullptr, sf, 768);

    recon_loss_k<<<dim3(B_, 4), 256, 0, stream>>>(feats, out_attn, sf, parts);
    loss_final_k<<<1, 512, 0, stream>>>(parts, out_loss);
}

// Round 18
// 186.917 us; speedup vs baseline: 1.1038x; 1.0549x over previous
//
#include <hip/hip_runtime.h>
#include <hip/hip_bf16.h>
#include <math.h>

// ---------------- problem constants ----------------
#define B_    128
#define N_    196
#define E_    768
#define K_    8
#define D_    128
#define BNR   (B_*N_)        // 25088 rows
#define ITERS 5

// ws layout (float units)
#define OFF_PART   0          // 512
#define OFF_SDEC   512        // ushort[1024*128] = 65536 floats
#define OFF_WBF    66048      // ushort region (incl. WMt)
#define OFF_KPBF   639488     // ushort[128*208*128]
#define OFF_VPTBF  2343424    // ushort[128*128*224]
#define OFF_ABF    4178432    // ushort[25088*768] (aliased by sf/h1/h2 after proj)

typedef __attribute__((ext_vector_type(8))) short bf16x8;
typedef __attribute__((ext_vector_type(4))) float f32x4;

#define MFMA16(a, b, c) __builtin_amdgcn_mfma_f32_16x16x32_bf16(a, b, c, 0, 0, 0)

__device__ __forceinline__ float wave_red_sum64(float v) {
    #pragma unroll
    for (int o = 32; o > 0; o >>= 1) v += __shfl_xor(v, o);
    return v;
}

__device__ __forceinline__ unsigned short f2bf(float v) {
    union { float f; unsigned int u; } c; c.f = v;
    unsigned int u = c.u + 0x7fffu + ((c.u >> 16) & 1u);  // RNE
    return (unsigned short)(u >> 16);
}

__device__ __forceinline__ void gl_lds16(const void* g, void* l) {
    __builtin_amdgcn_global_load_lds(
        (const __attribute__((address_space(1))) unsigned int*)g,
        (__attribute__((address_space(3))) unsigned int*)l, 16, 0, 0);
}

// chunk-XOR swizzled LDS addressing (8-bf16 = 16B chunks)
__device__ __forceinline__ int swz128(int row, int j) {
    return row * 128 + ((((j >> 3) ^ (row & 7))) << 3) + (j & 7);
}
__device__ __forceinline__ int swz256(int row, int j) {
    return row * 256 + ((((j >> 3) ^ (row & 7))) << 3) + (j & 7);
}
__device__ __forceinline__ bf16x8 ldA128(const unsigned short* base, int row, int kq, int ks) {
    int ch = (ks * 4 + kq) ^ (row & 7);
    return *(const bf16x8*)(base + row * 128 + ch * 8);
}
__device__ __forceinline__ bf16x8 ldA256(const unsigned short* base, int row, int kq, int ks) {
    int ch = (ks * 4 + kq) ^ (row & 7);
    return *(const bf16x8*)(base + row * 256 + ch * 8);
}
__device__ __forceinline__ bf16x8 ldW128(const unsigned short* W, int row, int ks, int kq) {
    return *(const bf16x8*)(W + (size_t)row * 128 + ks * 32 + kq * 8);
}

// ---------------- K0: merged prep + LN(features):
// blocks 0-5: wfold; 6-517: weight conversions; 518-1157: pad zeroing;
// 1158+: one-pass LayerNorm(features)->bf16 (independent of prep; overlapped here)
struct WCEnt { const float* s; unsigned short* d; int t0; };
struct WCArgs { WCEnt m[8]; };

__global__ __launch_bounds__(256) void prep_ln_k(const float* __restrict__ Wq,
                                                 const float* __restrict__ Wk,
                                                 unsigned short* __restrict__ WMt,
                                                 WCArgs a,
                                                 unsigned short* __restrict__ kpb,
                                                 unsigned short* __restrict__ vpt,
                                                 const float* __restrict__ feats,
                                                 const float* __restrict__ lng,
                                                 const float* __restrict__ lnb,
                                                 unsigned short* __restrict__ Abf) {
    __shared__ __align__(16) unsigned short Aq[128 * 128];
    __shared__ __align__(16) unsigned short Bk[128 * 128];
    int bid = blockIdx.x;
    int t = threadIdx.x;
    if (bid >= 1158) {
        // ---- LN path: one wave per feature row ----
        int wid = (bid - 1158) * 4 + (t >> 6);
        int lane = t & 63;
        const float* row = feats + (size_t)wid * E_;
        float4 x[3];
        float s = 0.f, s2 = 0.f;
        #pragma unroll
        for (int c = 0; c < 3; ++c) {
            x[c] = *(const float4*)(row + c * 256 + lane * 4);
            s  += x[c].x + x[c].y + x[c].z + x[c].w;
            s2 += x[c].x * x[c].x + x[c].y * x[c].y + x[c].z * x[c].z + x[c].w * x[c].w;
        }
        s  = wave_red_sum64(s);
        s2 = wave_red_sum64(s2);
        float m = s * (1.f / E_);
        float rs = rsqrtf(s2 * (1.f / E_) - m * m + 1e-5f);
        #pragma unroll
        for (int c = 0; c < 3; ++c) {
            float4 g4 = *(const float4*)(lng + c * 256 + lane * 4);
            float4 b4 = *(const float4*)(lnb + c * 256 + lane * 4);
            ushort4 o;
            o.x = f2bf((x[c].x - m) * rs * g4.x + b4.x);
            o.y = f2bf((x[c].y - m) * rs * g4.y + b4.y);
            o.z = f2bf((x[c].z - m) * rs * g4.z + b4.z);
            o.w = f2bf((x[c].w - m) * rs * g4.w + b4.w);
            *(ushort4*)(Abf + (size_t)wid * E_ + c * 256 + lane * 4) = o;
        }
        return;
    }
    if (bid < 6) {
        const float s = 0.08838834764831845f;  // 128^-0.5
        int e0 = bid * 128;
        for (int idx = t; idx < 16384; idx += 256) {
            int o = idx >> 7, c = idx & 127;
            Aq[swz128(c, o)] = f2bf(Wq[(size_t)o * 128 + c]);           // Aq[i][o] = Wq[o][i]
            Bk[swz128(c, o)] = f2bf(Wk[(size_t)o * 768 + e0 + c] * s);  // Bk[e][o] = s*Wk[o][e]
        }
        __syncthreads();
        int w = t >> 6, l = t & 63;
        int wr = w >> 1, wc = w & 1, fr = l & 15, kq = l >> 4;
        f32x4 acc[4][4];
        #pragma unroll
        for (int mi = 0; mi < 4; ++mi)
            #pragma unroll
            for (int nj = 0; nj < 4; ++nj) acc[mi][nj] = (f32x4){0.f, 0.f, 0.f, 0.f};
        #pragma unroll
        for (int ks = 0; ks < 4; ++ks) {
            bf16x8 af[4], bfr[4];
            #pragma unroll
            for (int mi = 0; mi < 4; ++mi) af[mi] = ldA128(Aq, wr * 64 + mi * 16 + fr, kq, ks);
            #pragma unroll
            for (int nj = 0; nj < 4; ++nj) bfr[nj] = ldA128(Bk, wc * 64 + nj * 16 + fr, kq, ks);
            #pragma unroll
            for (int mi = 0; mi < 4; ++mi)
                #pragma unroll
                for (int nj = 0; nj < 4; ++nj)
                    acc[mi][nj] = MFMA16(af[mi], bfr[nj], acc[mi][nj]);
        }
        #pragma unroll
        for (int mi = 0; mi < 4; ++mi) {
            int rowbase = wr * 64 + mi * 16 + kq * 4;
            #pragma unroll
            for (int nj = 0; nj < 4; ++nj) {
                int col = e0 + wc * 64 + nj * 16 + fr;
                #pragma unroll
                for (int r = 0; r < 4; ++r)
                    WMt[(size_t)(rowbase + r) * 768 + col] = f2bf(acc[mi][nj][r]);
            }
        }
    } else if (bid < 518) {
        int cbid = bid - 6, i = 0;
        #pragma unroll
        for (int j = 1; j < 8; ++j) if (cbid >= a.m[j].t0) i = j;
        int off = (cbid - a.m[i].t0) * 2048 + t * 8;
        const float* s = a.m[i].s + off;
        unsigned short* d = a.m[i].d + off;
        float4 v0 = *(const float4*)s, v1 = *(const float4*)(s + 4);
        ushort4 o0, o1;
        o0.x = f2bf(v0.x); o0.y = f2bf(v0.y); o0.z = f2bf(v0.z); o0.w = f2bf(v0.w);
        o1.x = f2bf(v1.x); o1.y = f2bf(v1.y); o1.z = f2bf(v1.z); o1.w = f2bf(v1.w);
        *(ushort4*)d = o0; *(ushort4*)(d + 4) = o1;
    } else {
        int i = (bid - 518) * 256 + t;   // ushort4 index, 163840 total
        ushort4 z = {0, 0, 0, 0};
        if (i < 49152) {                 // kp pads: 128 b x 12 rows x 128
            int q = i * 4;
            int b = q / 1536, off = q - b * 1536;
            *(ushort4*)(kpb + ((size_t)b * 208 + 196) * 128 + off) = z;
        } else {                          // vpT pads: per (b,d) cols 196..223
            int c = i - 49152;            // 0..114687
            int bd = c / 7, cc = c - bd * 7;
            *(ushort4*)(vpt + (size_t)bd * 224 + 196 + cc * 4) = z;
        }
    }
}

// ---------------- K2: dual-output bf16 MFMA GEMM: kpq (row-major) + vpT (LDS-transposed) ----------------
__global__ __launch_bounds__(512) void mfma_proj_k(const unsigned short* __restrict__ Abf,
                                                   const unsigned short* __restrict__ WMt,
                                                   const unsigned short* __restrict__ Wv_bf,
                                                   unsigned short* __restrict__ kpq_bf,
                                                   unsigned short* __restrict__ vpT_bf) {
    __shared__ __align__(16) unsigned short As[128 * 64];   // 1024 chunks
    __shared__ __align__(16) unsigned short Bs[256 * 64];   // 2048 chunks; reused as transpose buf
    const int t = threadIdx.x, w = t >> 6, l = t & 63;
    const int m0 = blockIdx.x * 128;
    const int wr = w >> 2, wc = w & 3;
    const int fr = l & 15, kq = l >> 4;
    f32x4 acc[4][4];
    #pragma unroll
    for (int mi = 0; mi < 4; ++mi)
        #pragma unroll
        for (int nj = 0; nj < 4; ++nj) acc[mi][nj] = (f32x4){0.f, 0.f, 0.f, 0.f};

    for (int ks = 0; ks < E_; ks += 64) {
        __syncthreads();
        #pragma unroll
        for (int j = 0; j < 2; ++j) {      // A: 1024 chunks
            int ci = j * 512 + (w << 6) + l;
            int r = ci >> 3, c = ci & 7, cg = c ^ (r & 7);
            gl_lds16(Abf + (size_t)(m0 + r) * E_ + ks + cg * 8,
                     As + (size_t)(j * 512 + (w << 6)) * 8);
        }
        #pragma unroll
        for (int j = 0; j < 4; ++j) {      // B: 2048 chunks (256 rows)
            int ci = j * 512 + (w << 6) + l;
            int r = ci >> 3, c = ci & 7, cg = c ^ (r & 7);
            const unsigned short* src = (r < 128)
                ? WMt   + (size_t)r * E_ + ks + cg * 8
                : Wv_bf + (size_t)(r - 128) * E_ + ks + cg * 8;
            gl_lds16(src, Bs + (size_t)(j * 512 + (w << 6)) * 8);
        }
        __syncthreads();
        #pragma unroll
        for (int kk = 0; kk < 2; ++kk) {
            bf16x8 af[4], bfr[4];
            #pragma unroll
            for (int mi = 0; mi < 4; ++mi) {
                int rr = wr * 64 + mi * 16 + fr;
                af[mi] = *(const bf16x8*)(As + rr * 64 + (((kk * 4 + kq) ^ (rr & 7))) * 8);
            }
            #pragma unroll
            for (int nj = 0; nj < 4; ++nj) {
                int rr = wc * 64 + nj * 16 + fr;
                bfr[nj] = *(const bf16x8*)(Bs + rr * 64 + (((kk * 4 + kq) ^ (rr & 7))) * 8);
            }
            #pragma unroll
            for (int mi = 0; mi < 4; ++mi)
                #pragma unroll
                for (int nj = 0; nj < 4; ++nj)
                    acc[mi][nj] = MFMA16(af[mi], bfr[nj], acc[mi][nj]);
        }
    }
    __syncthreads();   // all LDS MFMA reads complete before Bs reuse
    if (wc < 2) {
        // kpq quadrants: row-major padded per-batch writes
        #pragma unroll
        for (int mi = 0; mi < 4; ++mi) {
            int rowbase = m0 + wr * 64 + mi * 16 + kq * 4;
            #pragma unroll
            for (int r = 0; r < 4; ++r) {
                int m = rowbase + r;
                int b = m / 196, rr = m - b * 196;
                size_t o = ((size_t)b * 208 + rr) * 128;
                #pragma unroll
                for (int nj = 0; nj < 4; ++nj)
                    kpq_bf[o + wc * 64 + nj * 16 + fr] = f2bf(acc[mi][nj][r]);
            }
        }
    } else {
        // vp quadrants: transpose into Bs[d][tok] with XOR chunk swizzle
        int dbase = (wc - 2) * 64;
        #pragma unroll
        for (int mi = 0; mi < 4; ++mi) {
            int tok = wr * 64 + mi * 16 + kq * 4;
            #pragma unroll
            for (int nj = 0; nj < 4; ++nj) {
                int d = dbase + nj * 16 + fr;
                ushort4 pk;
                pk.x = f2bf(acc[mi][nj][0]); pk.y = f2bf(acc[mi][nj][1]);
                pk.z = f2bf(acc[mi][nj][2]); pk.w = f2bf(acc[mi][nj][3]);
                *(ushort4*)(Bs + d * 128 + (tok ^ ((d & 7) << 3))) = pk;
            }
        }
    }
    __syncthreads();
    // coalesced vpT store: thread t -> d = t>>2, m-range (t&3)*32..+32
    {
        int d = t >> 2, mg = t & 3;
        #pragma unroll
        for (int sc = 0; sc < 4; ++sc) {
            int mstart = mg * 32 + sc * 8;
            int cm = mstart >> 3;
            const unsigned short* src = Bs + d * 128 + ((cm ^ (d & 7)) << 3);
            int g0 = m0 + mstart;
            int b0 = g0 / 196, rr0 = g0 - b0 * 196;
            int b7 = (g0 + 7) / 196;
            if (b0 == b7) {
                unsigned short* dst = vpT_bf + ((size_t)b0 * 128 + d) * 224 + rr0;
                *(ushort4*)(dst)     = *(const ushort4*)(src);
                *(ushort4*)(dst + 4) = *(const ushort4*)(src + 4);
            } else {
                #pragma unroll
                for (int e = 0; e < 8; ++e) {
                    int g = g0 + e;
                    int bb = g / 196, rr = g - bb * 196;
                    vpT_bf[((size_t)bb * 128 + d) * 224 + rr] = src[e];
                }
            }
        }
    }
}

// ---------------- K2b: generic MLP-layer MFMA GEMM (R6-proven staging) ----------------
template<int KTOT, int EPI>
__global__ __launch_bounds__(256) void mfma_mlp_k(const unsigned short* __restrict__ A,
                                                  const unsigned short* __restrict__ Bw,
                                                  const float* __restrict__ bias,
                                                  unsigned short* __restrict__ out_bf,
                                                  float* __restrict__ out_f,
                                                  int ldN) {
    __shared__ __align__(16) unsigned short As[128 * 64];
    __shared__ __align__(16) unsigned short Bs[128 * 64];
    const int t = threadIdx.x, w = t >> 6, l = t & 63;
    const int m0 = blockIdx.x * 128;
    const int n0 = blockIdx.y * 128;
    const int wr = w >> 1, wc = w & 1;
    const int fr = l & 15, kq = l >> 4;
    f32x4 acc[4][4];
    #pragma unroll
    for (int mi = 0; mi < 4; ++mi)
        #pragma unroll
        for (int nj = 0; nj < 4; ++nj) acc[mi][nj] = (f32x4){0.f, 0.f, 0.f, 0.f};

    for (int ks = 0; ks < KTOT; ks += 64) {
        __syncthreads();
        #pragma unroll
        for (int j = 0; j < 4; ++j) {
            int ci = (w << 8) + (j << 6) + l;
            int r = ci >> 3, c = ci & 7;
            int cg = c ^ (r & 7);
            gl_lds16(A  + (size_t)(m0 + r) * KTOT + ks + cg * 8,
                     As + (size_t)((w << 8) + (j << 6)) * 8);
            gl_lds16(Bw + (size_t)(n0 + r) * KTOT + ks + cg * 8,
                     Bs + (size_t)((w << 8) + (j << 6)) * 8);
        }
        __syncthreads();
        #pragma unroll
        for (int kk = 0; kk < 2; ++kk) {
            bf16x8 af[4], bfr[4];
            int ch = (kk * 4 + kq) ^ (fr & 7);
            #pragma unroll
            for (int mi = 0; mi < 4; ++mi)
                af[mi] = *(const bf16x8*)(As + (wr * 64 + mi * 16 + fr) * 64 + ch * 8);
            #pragma unroll
            for (int nj = 0; nj < 4; ++nj)
                bfr[nj] = *(const bf16x8*)(Bs + (wc * 64 + nj * 16 + fr) * 64 + ch * 8);
            #pragma unroll
            for (int mi = 0; mi < 4; ++mi)
                #pragma unroll
                for (int nj = 0; nj < 4; ++nj)
                    acc[mi][nj] = MFMA16(af[mi], bfr[nj], acc[mi][nj]);
        }
    }
    #pragma unroll
    for (int mi = 0; mi < 4; ++mi) {
        int rowbase = m0 + wr * 64 + mi * 16 + kq * 4;
        #pragma unroll
        for (int nj = 0; nj < 4; ++nj) {
            int col = n0 + wc * 64 + nj * 16 + fr;
            float bc = bias[col];
            #pragma unroll
            for (int r = 0; r < 4; ++r) {
                float v = acc[mi][nj][r] + bc;
                if (EPI == 0)
                    out_bf[(size_t)(rowbase + r) * ldN + col] = f2bf(fmaxf(v, 0.f));
                else
                    out_f[(size_t)(rowbase + r) * ldN + col] = v;
            }
        }
    }
}

// ---------------- K3: persistent per-batch slot-attention iterations (MFMA) ----------------
// R10/R15 8-phase structure (proven 64 us). No register hoists: hipcc caps
// 512-thread kernels at 128 VGPR and rematerializes/spills any hoist (R11/R12/R15).
__global__ __launch_bounds__(512) void slot_iter_mfma(
    const float* __restrict__ noise,
    const float* __restrict__ lsg, const float* __restrict__ lsb,
    const float* __restrict__ log_, const float* __restrict__ lob,
    const float* __restrict__ ldg_, const float* __restrict__ ldb_,
    const float* __restrict__ mup, const float* __restrict__ lsig,
    const unsigned short* __restrict__ Wih_bf,
    const unsigned short* __restrict__ Whh_bf,
    const float* __restrict__ bih, const float* __restrict__ bhh,
    const unsigned short* __restrict__ W1_bf, const float* __restrict__ mb1,
    const unsigned short* __restrict__ W2_bf, const float* __restrict__ mb2,
    const unsigned short* __restrict__ kpq_bf,
    const unsigned short* __restrict__ vpT_bf,
    float* __restrict__ out_slots, float* __restrict__ out_attn,
    unsigned short* __restrict__ sdec_bf) {

    __shared__ float slots[8][128];
    __shared__ float attn[208][9];
    __shared__ float colpart[8][8];
    __shared__ __align__(16) unsigned short sln_bf[2048];
    __shared__ __align__(16) unsigned short upd_bf[2048];
    __shared__ __align__(16) unsigned short slots_bf[2048];
    __shared__ __align__(16) unsigned short h_bf[2048];
    __shared__ __align__(16) unsigned short attnT_bf[4096];

    const int b = blockIdx.x, t = threadIdx.x;
    const int lane = t & 63, w = t >> 6;
    const int fr = lane & 15, kq = lane >> 4;

    for (int i = t; i < 2048; i += 512) {
        sln_bf[i] = 0; upd_bf[i] = 0; slots_bf[i] = 0; h_bf[i] = 0;
    }
    for (int i = t; i < 4096; i += 512) attnT_bf[i] = 0;

    for (int idx = t; idx < 1024; idx += 512) {
        int k = idx >> 7, d = idx & 127;
        float v = noise[(size_t)b * 1024 + idx] * expf(lsig[d]) + mup[d];
        slots[k][d] = v;
        slots_bf[swz128(k, d)] = f2bf(v);
    }
    __syncthreads();

    for (int it = 0; it < ITERS; ++it) {
        bool last = (it == ITERS - 1);
        // (a) LN_slot -> sln_bf (wave w owns slot w)
        {
            float x0 = slots[w][lane], x1 = slots[w][lane + 64];
            float s  = wave_red_sum64(x0 + x1);
            float s2 = wave_red_sum64(x0 * x0 + x1 * x1);
            float m = s * 0.0078125f;
            float rs = rsqrtf(s2 * 0.0078125f - m * m + 1e-5f);
            sln_bf[swz128(w, lane)]      = f2bf((x0 - m) * rs * lsg[lane]      + lsb[lane]);
            sln_bf[swz128(w, lane + 64)] = f2bf((x1 - m) * rs * lsg[lane + 64] + lsb[lane + 64]);
        }
        __syncthreads();
        // (c) logits = kpq @ sln^T, softmax over slots -> attn LDS + colpart
        {
            float cp = 0.f;
            #pragma unroll
            for (int p = 0; p < 2; ++p) {
                int tt = w + p * 8;
                if (tt <= 12) {
                    f32x4 acc = {0.f, 0.f, 0.f, 0.f};
                    const unsigned short* kpr = kpq_bf + ((size_t)b * 208 + tt * 16 + fr) * 128;
                    #pragma unroll
                    for (int ks = 0; ks < 4; ++ks)
                        acc = MFMA16(*(const bf16x8*)(kpr + ks * 32 + kq * 8),
                                     ldA128(sln_bf, fr, kq, ks), acc);
                    #pragma unroll
                    for (int r = 0; r < 4; ++r) {
                        float v = acc[r];
                        float mx = fmaxf(v, __shfl_xor(v, 1));
                        mx = fmaxf(mx, __shfl_xor(mx, 2));
                        mx = fmaxf(mx, __shfl_xor(mx, 4));
                        float e = expf(v - mx);
                        float sm = e;
                        sm += __shfl_xor(sm, 1); sm += __shfl_xor(sm, 2); sm += __shfl_xor(sm, 4);
                        float a = e / sm;
                        int tok = tt * 16 + kq * 4 + r;
                        bool valid = (tok < 196);
                        if (fr < 8 && valid) attn[tok][fr] = a;
                        cp += valid ? a : 0.f;
                    }
                }
            }
            cp += __shfl_xor(cp, 16);
            cp += __shfl_xor(cp, 32);
            if (lane < 8) colpart[w][lane] = cp;
        }
        __syncthreads();
        // (e) normalize over tokens -> attnT_bf (+ out_attn last iter)
        {
            int k = t & 7;
            float cs = colpart[0][k] + colpart[1][k] + colpart[2][k] + colpart[3][k]
                     + colpart[4][k] + colpart[5][k] + colpart[6][k] + colpart[7][k]
                     + 196.0f * 1e-8f;
            float inv = 1.f / cs;
            for (int idx = t; idx < 1568; idx += 512) {
                int n = idx >> 3;
                float raw = attn[n][k];
                attnT_bf[swz256(k, n)] = f2bf((raw + 1e-8f) * inv);
                if (last) out_attn[((size_t)b * 196 + n) * 8 + k] = raw;
            }
        }
        __syncthreads();
        // (f) updates = attn_norm^T @ v -> upd_bf
        {
            f32x4 acc = {0.f, 0.f, 0.f, 0.f};
            const unsigned short* vpr = vpT_bf + ((size_t)b * 128 + w * 16 + fr) * 224;
            #pragma unroll
            for (int ks = 0; ks < 7; ++ks)
                acc = MFMA16(ldA256(attnT_bf, fr, kq, ks),
                             *(const bf16x8*)(vpr + ks * 32 + kq * 8), acc);
            if (kq < 2) {
                #pragma unroll
                for (int r = 0; r < 4; ++r)
                    upd_bf[swz128(kq * 4 + r, w * 16 + fr)] = f2bf(acc[r]);
            }
        }
        __syncthreads();
        // (g) GRU
        {
            f32x4 gi0 = {0,0,0,0}, gi1 = {0,0,0,0}, gi2 = {0,0,0,0};
            f32x4 gh0 = {0,0,0,0}, gh1 = {0,0,0,0}, gh2 = {0,0,0,0};
            #pragma unroll
            for (int ks = 0; ks < 4; ++ks) {
                bf16x8 au = ldA128(upd_bf,   fr, kq, ks);
                bf16x8 as = ldA128(slots_bf, fr, kq, ks);
                gi0 = MFMA16(au, ldW128(Wih_bf,       w * 16 + fr, ks, kq), gi0);
                gi1 = MFMA16(au, ldW128(Wih_bf, 128 + w * 16 + fr, ks, kq), gi1);
                gi2 = MFMA16(au, ldW128(Wih_bf, 256 + w * 16 + fr, ks, kq), gi2);
                gh0 = MFMA16(as, ldW128(Whh_bf,       w * 16 + fr, ks, kq), gh0);
                gh1 = MFMA16(as, ldW128(Whh_bf, 128 + w * 16 + fr, ks, kq), gh1);
                gh2 = MFMA16(as, ldW128(Whh_bf, 256 + w * 16 + fr, ks, kq), gh2);
            }
            if (kq < 2) {
                int d = w * 16 + fr;
                float bi0 = bih[d], bi1 = bih[128 + d], bi2 = bih[256 + d];
                float bh0 = bhh[d], bh1 = bhh[128 + d], bh2 = bhh[256 + d];
                #pragma unroll
                for (int r = 0; r < 4; ++r) {
                    int m = kq * 4 + r;
                    float rr = 1.f / (1.f + expf(-((gi0[r] + bi0) + (gh0[r] + bh0))));
                    float zz = 1.f / (1.f + expf(-((gi1[r] + bi1) + (gh1[r] + bh1))));
                    float nn = tanhf((gi2[r] + bi2) + rr * (gh2[r] + bh2));
                    float h = slots[m][d];
                    slots[m][d] = (1.f - zz) * nn + zz * h;
                }
            }
        }
        __syncthreads();
        // (h) LN_out -> sln_bf
        {
            float x0 = slots[w][lane], x1 = slots[w][lane + 64];
            float s  = wave_red_sum64(x0 + x1);
            float s2 = wave_red_sum64(x0 * x0 + x1 * x1);
            float m = s * 0.0078125f;
            float rs = rsqrtf(s2 * 0.0078125f - m * m + 1e-5f);
            sln_bf[swz128(w, lane)]      = f2bf((x0 - m) * rs * log_[lane]      + lob[lane]);
            sln_bf[swz128(w, lane + 64)] = f2bf((x1 - m) * rs * log_[lane + 64] + lob[lane + 64]);
        }
        __syncthreads();
        // (i) MLP1 -> h_bf
        {
            f32x4 acc = {0.f, 0.f, 0.f, 0.f};
            #pragma unroll
            for (int ks = 0; ks < 4; ++ks)
                acc = MFMA16(ldA128(sln_bf, fr, kq, ks), ldW128(W1_bf, w * 16 + fr, ks, kq), acc);
            if (kq < 2) {
                float b1 = mb1[w * 16 + fr];
                #pragma unroll
                for (int r = 0; r < 4; ++r)
                    h_bf[swz128(kq * 4 + r, w * 16 + fr)] = f2bf(fmaxf(acc[r] + b1, 0.f));
            }
        }
        __syncthreads();
        // (j) MLP2 residual -> slots, slots_bf
        {
            f32x4 acc = {0.f, 0.f, 0.f, 0.f};
            #pragma unroll
            for (int ks = 0; ks < 4; ++ks)
                acc = MFMA16(ldA128(h_bf, fr, kq, ks), ldW128(W2_bf, w * 16 + fr, ks, kq), acc);
            if (kq < 2) {
                float b2 = mb2[w * 16 + fr];
                #pragma unroll
                for (int r = 0; r < 4; ++r) {
                    int m = kq * 4 + r, d = w * 16 + fr;
                    float v = slots[m][d] + acc[r] + b2;
                    slots[m][d] = v;
                    slots_bf[swz128(m, d)] = f2bf(v);
                }
            }
        }
        __syncthreads();
    }
    // epilogue: raw slots out + fused LN_dec -> sdec_bf
    {
        float x0 = slots[w][lane], x1 = slots[w][lane + 64];
        out_slots[(size_t)b * 1024 + w * 128 + lane]      = x0;
        out_slots[(size_t)b * 1024 + w * 128 + lane + 64] = x1;
        float s  = wave_red_sum64(x0 + x1);
        float s2 = wave_red_sum64(x0 * x0 + x1 * x1);
        float m = s * 0.0078125f;
        float rs = rsqrtf(s2 * 0.0078125f - m * m + 1e-5f);
        sdec_bf[((size_t)b * 8 + w) * 128 + lane]      = f2bf((x0 - m) * rs * ldg_[lane]      + ldb_[lane]);
        sdec_bf[((size_t)b * 8 + w) * 128 + lane + 64] = f2bf((x1 - m) * rs * ldg_[lane + 64] + ldb_[lane + 64]);
    }
}

// ---------------- K5: fused recon + squared-error partial sums ----------------
__global__ __launch_bounds__(256) void recon_loss_k(
    const float* __restrict__ feats, const float* __restrict__ attnv,
    const float* __restrict__ sf, float* __restrict__ partials) {

    __shared__ float sfl[8][768];
    __shared__ float al[49][8];
    __shared__ float wred[4];
    int b = blockIdx.x, qd = blockIdx.y, t = threadIdx.x;
    for (int idx = t; idx < 8 * 768; idx += 256)
        ((float*)sfl)[idx] = sf[(size_t)b * 8 * 768 + idx];
    int n0 = qd * 49;
    for (int idx = t; idx < 49 * 8; idx += 256)
        ((float*)al)[idx] = attnv[((size_t)b * N_ + n0) * 8 + idx];
    __syncthreads();
    float acc = 0.f;
    for (int nl = 0; nl < 49; ++nl) {
        float a0 = al[nl][0], a1 = al[nl][1], a2 = al[nl][2], a3 = al[nl][3];
        float a4 = al[nl][4], a5 = al[nl][5], a6 = al[nl][6], a7 = al[nl][7];
        const float* frow = feats + ((size_t)(b * N_ + n0 + nl)) * E_;
        for (int c = t; c < E_; c += 256) {
            float r = sfl[0][c]*a0 + sfl[1][c]*a1 + sfl[2][c]*a2 + sfl[3][c]*a3
                    + sfl[4][c]*a4 + sfl[5][c]*a5 + sfl[6][c]*a6 + sfl[7][c]*a7;
            float d = r - frow[c];
            acc += d * d;
        }
    }
    acc = wave_red_sum64(acc);
    int lane = t & 63, w = t >> 6;
    if (lane == 0) wred[w] = acc;
    __syncthreads();
    if (t == 0) partials[b * 4 + qd] = wred[0] + wred[1] + wred[2] + wred[3];
}

__global__ __launch_bounds__(512) void loss_final_k(const float* __restrict__ partials,
                                                    float* __restrict__ out) {
    __shared__ float wred[8];
    int t = threadIdx.x;
    float v = partials[t];
    v = wave_red_sum64(v);
    if ((t & 63) == 0) wred[t >> 6] = v;
    __syncthreads();
    if (t == 0) {
        float s = 0.f;
        #pragma unroll
        for (int i = 0; i < 8; ++i) s += wred[i];
        out[0] = s / (float)(B_ * N_ * E_);
    }
}

// ---------------- launch ----------------
extern "C" void kernel_launch(void* const* d_in, const int* in_sizes, int n_in,
                              void* d_out, int out_size, void* d_ws, size_t ws_size,
                              hipStream_t stream) {
    (void)in_sizes; (void)n_in; (void)out_size; (void)ws_size;
    const float* feats     = (const float*)d_in[0];
    const float* noise     = (const float*)d_in[1];
    const float* ln_in_g   = (const float*)d_in[2];
    const float* ln_in_b   = (const float*)d_in[3];
    const float* ln_slot_g = (const float*)d_in[4];
    const float* ln_slot_b = (const float*)d_in[5];
    const float* ln_out_g  = (const float*)d_in[6];
    const float* ln_out_b  = (const float*)d_in[7];
    const float* ln_dec_g  = (const float*)d_in[8];
    const float* ln_dec_b  = (const float*)d_in[9];
    const float* mu        = (const float*)d_in[10];
    const float* log_sigma = (const float*)d_in[11];
    const float* Wk        = (const float*)d_in[12];
    const float* Wq        = (const float*)d_in[13];
    const float* Wv        = (const float*)d_in[14];
    const float* W_ih      = (const float*)d_in[15];
    const float* W_hh      = (const float*)d_in[16];
    const float* b_ih      = (const float*)d_in[17];
    const float* b_hh      = (const float*)d_in[18];
    const float* mlp_W1    = (const float*)d_in[19];
    const float* mlp_b1    = (const float*)d_in[20];
    const float* mlp_W2    = (const float*)d_in[21];
    const float* mlp_b2    = (const float*)d_in[22];
    const float* dec_W1    = (const float*)d_in[23];
    const float* dec_b1    = (const float*)d_in[24];
    const float* dec_W2    = (const float*)d_in[25];
    const float* dec_b2    = (const float*)d_in[26];
    const float* dec_W3    = (const float*)d_in[27];
    const float* dec_b3    = (const float*)d_in[28];

    float* ws    = (float*)d_ws;
    float* parts = ws + OFF_PART;
    unsigned short* sdec_bf = (unsigned short*)(ws + OFF_SDEC);   // [1024][128]
    unsigned short* Wbase   = (unsigned short*)(ws + OFF_WBF);
    unsigned short* Wv_bf   = Wbase;              // [128][768]
    unsigned short* Wih_bf  = Wbase + 98304;      // [384][128]
    unsigned short* Whh_bf  = Wbase + 147456;     // [384][128]
    unsigned short* W1_bf   = Wbase + 196608;     // [128][128]
    unsigned short* W2_bf   = Wbase + 212992;     // [128][128]
    unsigned short* dW1_bf  = Wbase + 229376;     // [256][128]
    unsigned short* dW2_bf  = Wbase + 262144;     // [768][256]
    unsigned short* dW3_bf  = Wbase + 458752;     // [768][768]
    unsigned short* WMt     = Wbase + 1048576;    // [128][768]
    unsigned short* kpq_bf  = (unsigned short*)(ws + OFF_KPBF);   // [128][208][128]
    unsigned short* vpT_bf  = (unsigned short*)(ws + OFF_VPTBF);  // [128][128][224]
    unsigned short* Abf     = (unsigned short*)(ws + OFF_ABF);    // [25088][768]
    // decoder intermediates alias the Abf region (dead after mfma_proj_k)
    float*          sf      = ws + OFF_ABF;                        // [1024][768] fp32
    unsigned short* h1_bf   = (unsigned short*)(ws + OFF_ABF + 786432);           // [1024][256]
    unsigned short* h2_bf   = (unsigned short*)(ws + OFF_ABF + 786432 + 131072);  // [1024][768]

    float* out_slots = (float*)d_out;               // [128,8,128]
    float* out_attn  = out_slots + 131072;          // [128,196,8]
    float* out_loss  = out_slots + 331776;          // scalar

    WCArgs wa;
    wa.m[0] = {Wv,     Wv_bf,  0};     // 48 blocks
    wa.m[1] = {W_ih,   Wih_bf, 48};    // 24
    wa.m[2] = {W_hh,   Whh_bf, 72};    // 24
    wa.m[3] = {mlp_W1, W1_bf,  96};    // 8
    wa.m[4] = {mlp_W2, W2_bf,  104};   // 8
    wa.m[5] = {dec_W1, dW1_bf, 112};   // 16
    wa.m[6] = {dec_W2, dW2_bf, 128};   // 96
    wa.m[7] = {dec_W3, dW3_bf, 224};   // 288 -> 512 total conv
    // blocks: 6 wfold + 512 conv + 640 padzero + 6272 LN = 7430
    prep_ln_k<<<1158 + BNR / 4, 256, 0, stream>>>(Wq, Wk, WMt, wa, kpq_bf, vpT_bf,
                                                  feats, ln_in_g, ln_in_b, Abf);

    mfma_proj_k<<<BNR / 128, 512, 0, stream>>>(Abf, WMt, Wv_bf, kpq_bf, vpT_bf);

    slot_iter_mfma<<<B_, 512, 0, stream>>>(noise, ln_slot_g, ln_slot_b, ln_out_g, ln_out_b,
                                           ln_dec_g, ln_dec_b, mu, log_sigma,
                                           Wih_bf, Whh_bf, b_ih, b_hh,
                                           W1_bf, mlp_b1, W2_bf, mlp_b2, kpq_bf, vpT_bf,
                                           out_slots, out_attn, sdec_bf);

    // decoder: 3 bf16 MFMA GEMMs over M=1024
    mfma_mlp_k<128, 0><<<dim3(8, 2), 256, 0, stream>>>(sdec_bf, dW1_bf, dec_b1, h1_bf, nullptr, 256);
    mfma_mlp_k<256, 0><<<dim3(8, 6), 256, 0, stream>>>(h1_bf,  dW2_bf, dec_b2, h2_bf, nullptr, 768);
    mfma_mlp_k<768, 1><<<dim3(8, 6), 256, 0, stream>>>(h2_bf,  dW3_bf, dec_b3, nullptr, sf, 768);

    recon_loss_k<<<dim3(B_, 4), 256, 0, stream>>>(feats, out_attn, sf, parts);
    loss_final_k<<<1, 512, 0, stream>>>(parts, out_loss);
}